// Round 12
// baseline (1075.723 us; speedup 1.0000x reference)
//
#include <hip/hip_runtime.h>
#include <hip/hip_bf16.h>

// ---------------------------------------------------------------------------
// UNet3D dense forward, round 12: NDHWC implicit-GEMM MFMA.
//  - Reverted R11 reg-pipeline (VGPR 108->68; occupancy was the real lever).
//  - V0 stride-1 convs: tile 2d x 4h x 16w, LDS 27.6KB -> 5 blocks/CU
//    (was 46.6KB -> 3). Each wave: (d-slice, h-half) with 2 j-rows.
//  - BN fused at consumer LDS-write (s4/r32/c32/r64/c64); stats raw.
//  - conv2: CO_TILES=1, y=8. tconvs as R10 (tconv1c CT4).
// ---------------------------------------------------------------------------

using bf16 = __hip_bfloat16;
using ushort4v = __attribute__((ext_vector_type(4))) unsigned short;
using ushort8  = __attribute__((ext_vector_type(8))) unsigned short;
using short8   = __attribute__((ext_vector_type(8))) short;
using f32x4    = __attribute__((ext_vector_type(4))) float;
using float4v  = __attribute__((ext_vector_type(4))) float;

#define TPB 256

static inline int cdiv_l(long a, int b){ return (int)((a + b - 1) / b); }

__device__ __forceinline__ float b2f(unsigned short u){
  union { unsigned int i; float f; } v; v.i = ((unsigned int)u) << 16; return v.f;
}
__device__ __forceinline__ unsigned short f2b(float f){
  union { bf16 h; unsigned short u; } v; v.h = __float2bfloat16(f); return v.u;
}
// BN+ReLU on 8 packed bf16 channels starting at channel c (8-aligned).
__device__ __forceinline__ ushort8 bnApply8(ushort8 v, const float* sc, const float* sh, int c){
  float4v s0 = *(const float4v*)(sc + c), s1v = *(const float4v*)(sc + c + 4);
  float4v h0 = *(const float4v*)(sh + c), h1v = *(const float4v*)(sh + c + 4);
  ushort8 r;
#pragma unroll
  for (int j = 0; j < 4; ++j){ float y = b2f(v[j]) * s0[j] + h0[j]; r[j] = f2b(y > 0.f ? y : 0.f); }
#pragma unroll
  for (int j = 0; j < 4; ++j){ float y = b2f(v[j+4]) * s1v[j] + h1v[j]; r[j+4] = f2b(y > 0.f ? y : 0.f); }
  return r;
}

// ---------------- weight repacks (bf16) ----------------
__global__ void rp_enc(const float* __restrict__ w, unsigned short* __restrict__ wb,
                       int Cin, int Cout){
  int idx = blockIdx.x * TPB + threadIdx.x;
  int tot = 27 * Cout * Cin; if (idx >= tot) return;
  int ci = idx % Cin; int t = idx / Cin; int co = t % Cout; int tap = t / Cout;
  wb[idx] = f2b(w[((long)co * Cin + ci) * 27 + tap]);
}
__global__ void rp_dec(const float* __restrict__ w, unsigned short* __restrict__ wb,
                       int Cin, int Cout, int CIP, int COP){
  int idx = blockIdx.x * TPB + threadIdx.x;
  int tot = 27 * COP * CIP; if (idx >= tot) return;
  int ci = idx % CIP; int t = idx / CIP; int co = t % COP; int tap = t / COP;
  float v = (ci < Cin && co < Cout) ? w[((long)tap * Cin + ci) * Cout + co] : 0.f;
  wb[idx] = f2b(v);
}
// conv0 tap-paired: [pp<14][co<32][k<32]
__global__ void rp_pair(const float* __restrict__ w, unsigned short* __restrict__ wb){
  int idx = blockIdx.x * TPB + threadIdx.x;
  int tot = 14 * 32 * 32; if (idx >= tot) return;
  int k = idx & 31; int t = idx >> 5; int co = t & 31; int pp = t >> 5;
  int tap = pp * 2 + (k >> 4); int ci = k & 15;
  float v = (tap < 27) ? w[((long)co * 16 + ci) * 27 + tap] : 0.f;
  wb[idx] = f2b(v);
}

// ---------------- x transpose: NCDHW fp32 -> NDHWC bf16 (C=16) ----------------
__global__ void xpose_k(const float* __restrict__ x, unsigned short* __restrict__ xt){
  __shared__ float l[16][257];
  int t = threadIdx.x;
  long p0 = (long)blockIdx.x * 256;
  int n = (int)(p0 >> 18);
  long off = p0 & 262143;
  const float* xb = x + ((long)n * 16) * 262144 + off;
#pragma unroll
  for (int c = 0; c < 16; ++c) l[c][t] = xb[(long)c * 262144 + t];
  __syncthreads();
  ushort8 u0, u1;
#pragma unroll
  for (int k = 0; k < 8; ++k){ u0[k] = f2b(l[k][t]); u1[k] = f2b(l[k + 8][t]); }
  unsigned short* o = xt + (p0 + t) * 16;
  *(ushort8*)o = u0; *(ushort8*)(o + 8) = u1;
}

// ---------------- quadrant stride-2 tconv, LDS-staged, fused BN on A -------
template <int CO_TILES>
__global__ __launch_bounds__(TPB, 2) void tconv_quad(
    const unsigned short* __restrict__ inA, int CA,
    const unsigned short* __restrict__ inB, int CB,
    const float* __restrict__ scA, const float* __restrict__ shA,
    const unsigned short* __restrict__ wb,
    unsigned short* __restrict__ out,
    int N, int Cout, int COP, int CIP, int G) {
  __shared__ unsigned short xs[4 * 432 * 8];
  const int tid = threadIdx.x, wv = tid >> 6, l = tid & 63, l15 = l & 15, lg = l >> 4;
  int ntW = G >> 4, ntH = G >> 2, ntD = G >> 2;
  int bx = blockIdx.x;
  int w0 = (bx % ntW) << 4; bx /= ntW;
  int h0 = (bx % ntH) << 2; bx /= ntH;
  int d0 = (bx % ntD) << 2; int n = bx / ntD;
  const int co0 = blockIdx.y * (16 * CO_TILES);
  const int quad = blockIdx.z;
  const int pd = (quad >> 1) & 1, ph = quad & 1;
  const long spin = (long)G * G * G;

  int nkd, kd_[2], dd_[2], nkh, kh_[2], dh_[2];
  if (pd){ nkd=1; kd_[0]=1; dd_[0]=0; } else { nkd=2; kd_[0]=0; dd_[0]=-1; kd_[1]=2; dd_[1]=0; }
  if (ph){ nkh=1; kh_[0]=1; dh_[0]=0; } else { nkh=2; kh_[0]=0; dh_[0]=-1; kh_[1]=2; dh_[1]=0; }

  f32x4 acc[CO_TILES][4][2];
#pragma unroll
  for (int ct = 0; ct < CO_TILES; ++ct)
#pragma unroll
    for (int j = 0; j < 4; ++j)
#pragma unroll
      for (int p = 0; p < 2; ++p) acc[ct][j][p] = (f32x4){0.f, 0.f, 0.f, 0.f};

  const int nch = CIP >> 5;
#pragma unroll 1
  for (int ch = 0; ch < nch; ++ch) {
    int c0 = ch << 5;
    const unsigned short* src; int Cs, cl_; bool useBN;
    if (c0 < CA){ src = inA; Cs = CA; cl_ = c0; useBN = (scA != nullptr); }
    else        { src = inB; Cs = CB; cl_ = c0 - CA; useBN = false; }
    const unsigned short* sb = src + (long)n * Cs * spin;
    __syncthreads();
    for (int idx = tid; idx < 4 * 425; idx += TPB) {
      int q = idx / 425, pt = idx - q * 425;
      int zw = pt % 17; int zt = pt / 17; int zh = zt % 5; int zd = zt / 5;
      int gd = d0 + zd - 1, gh = h0 + zh - 1, gw = w0 + zw - 1;
      ushort8 v = (ushort8){0,0,0,0,0,0,0,0};
      if ((unsigned)gd < (unsigned)G && (unsigned)gh < (unsigned)G && (unsigned)gw < (unsigned)G) {
        v = *(const ushort8*)(sb + (((long)gd * G + gh) * G + gw) * Cs + cl_ + q * 8);
        if (useBN) v = bnApply8(v, scA, shA, cl_ + q * 8);
      }
      *(ushort8*)(xs + (q * 432 + pt) * 8) = v;
    }
    __syncthreads();
#pragma unroll 1
    for (int a = 0; a < nkd; ++a) {
      int zd = wv + 1 + dd_[a];
#pragma unroll 1
      for (int b = 0; b < nkh; ++b) {
        int tapb = (kd_[a] * 3 + kh_[b]) * 3;
        const unsigned short* ap = wb + ((long)tapb * COP + co0 + l15) * CIP + c0 + lg * 8;
        long tstride = (long)COP * CIP;
        short8 Ak0[CO_TILES], Ak1[CO_TILES], Ak2[CO_TILES];
#pragma unroll
        for (int ct = 0; ct < CO_TILES; ++ct) {
          Ak0[ct] = *(const short8*)(ap + ct * 16 * CIP);
          Ak1[ct] = *(const short8*)(ap + tstride + ct * 16 * CIP);
          Ak2[ct] = *(const short8*)(ap + 2 * tstride + ct * 16 * CIP);
        }
        int zh0 = 1 + dh_[b];
#pragma unroll
        for (int j = 0; j < 4; ++j) {
          int basept = (zd * 5 + (j + zh0)) * 17 + l15;
          short8 Bm = *(const short8*)(xs + (lg * 432 + basept) * 8);
          short8 B0 = *(const short8*)(xs + (lg * 432 + basept + 1) * 8);
#pragma unroll
          for (int ct = 0; ct < CO_TILES; ++ct) {
            acc[ct][j][0] = __builtin_amdgcn_mfma_f32_16x16x32_bf16(Ak0[ct], Bm, acc[ct][j][0], 0, 0, 0);
            acc[ct][j][0] = __builtin_amdgcn_mfma_f32_16x16x32_bf16(Ak2[ct], B0, acc[ct][j][0], 0, 0, 0);
            acc[ct][j][1] = __builtin_amdgcn_mfma_f32_16x16x32_bf16(Ak1[ct], B0, acc[ct][j][1], 0, 0, 0);
          }
        }
      }
    }
  }

  // ---- dense store ----
  int Gout = 2 * G; long spo = (long)Gout * Gout * Gout;
  int od = 2 * (d0 + wv) + pd;
#pragma unroll
  for (int j = 0; j < 4; ++j) {
    int oh = 2 * (h0 + j) + ph;
#pragma unroll
    for (int p = 0; p < 2; ++p) {
      int ow = 2 * (w0 + l15) + p;
      long pt = ((long)od * Gout + oh) * Gout + ow;
#pragma unroll
      for (int ct = 0; ct < CO_TILES; ++ct) {
        ushort4v pk;
#pragma unroll
        for (int r = 0; r < 4; ++r) pk[r] = f2b(acc[ct][j][p][r]);
        *(ushort4v*)(out + ((long)n * spo + pt) * Cout + co0 + ct * 16 + lg * 4) = pk;
      }
    }
  }
}

// ---------------- unified NDHWC MFMA conv ----------------
// VARIANT 0 / PAIRED: stride-1 conv, LDS-staged, tile 2d x 4h x 16w.
//   wave wv: wvd = wv&1 (d-slice), jh = wv>>1 (h-half, 2 j-rows each).
// VARIANT 2: stride-2 conv, direct-global B, tile 4d x 4h x 16w.
template <int VARIANT, int CO_TILES, bool PAIRED, bool FOUT>
__global__ __launch_bounds__(TPB) void mconv(
    const unsigned short* __restrict__ inA, int CA,
    const unsigned short* __restrict__ inB, int CB,
    const float* __restrict__ scA, const float* __restrict__ shA,
    const unsigned short* __restrict__ wb,
    void* __restrict__ outv,
    int N, int Cout, int COP, int CIP, int G) {
  const int tid = threadIdx.x, wv = tid >> 6, l = tid & 63, l15 = l & 15, lg = l >> 4;
  int bx = blockIdx.x;
  int w0, h0, d0, n;
  int wvd = wv & 1, jh = wv >> 1, jbase = jh * 2;
  if constexpr (VARIANT == 0) {
    int ntW = G >> 4, ntH = G >> 2, ntD = G >> 1;
    w0 = (bx % ntW) << 4; bx /= ntW;
    h0 = (bx % ntH) << 2; bx /= ntH;
    d0 = (bx % ntD) << 1; n = bx / ntD;
  } else {
    int ntW = G >> 4, ntH = G >> 2, ntD = G >> 2;
    w0 = (bx % ntW) << 4; bx /= ntW;
    h0 = (bx % ntH) << 2; bx /= ntH;
    d0 = (bx % ntD) << 2; n = bx / ntD;
  }
  const int co0 = blockIdx.y * (16 * CO_TILES);
  const int Gin = (VARIANT == 2) ? 2 * G : G;
  const long spin = (long)Gin * Gin * Gin;

  constexpr int JR = (VARIANT == 0) ? 2 : 4;
  f32x4 acc[CO_TILES][JR];
#pragma unroll
  for (int ct = 0; ct < CO_TILES; ++ct)
#pragma unroll
    for (int j = 0; j < JR; ++j) acc[ct][j] = (f32x4){0.f, 0.f, 0.f, 0.f};

  if constexpr (PAIRED) {
    // conv0: Cin=16, K packs 2 taps; raw input (no BN). tile 2x4x16.
    __shared__ unsigned short xs[2 * 432 * 8];
    const unsigned short* src = inA + (long)n * 16 * spin;
    for (int idx = tid; idx < 2 * 432; idx += TPB) {
      int q = idx / 432, pt = idx - q * 432;
      int zw = pt % 18; int zt = pt / 18; int zh = zt % 6; int zd = zt / 6;
      int gd = d0 + zd - 1, gh = h0 + zh - 1, gw = w0 + zw - 1;
      ushort8 v = (ushort8){0,0,0,0,0,0,0,0};
      if ((unsigned)gd < (unsigned)G && (unsigned)gh < (unsigned)G && (unsigned)gw < (unsigned)G)
        v = *(const ushort8*)(src + (((long)gd * G + gh) * G + gw) * 16 + q * 8);
      *(ushort8*)(xs + (q * 432 + pt) * 8) = v;
    }
    __syncthreads();
#pragma unroll 1
    for (int pp = 0; pp < 14; ++pp) {
      short8 A0 = *(const short8*)(wb + ((pp * 32 + l15) * 32) + lg * 8);
      short8 A1 = *(const short8*)(wb + ((pp * 32 + 16 + l15) * 32) + lg * 8);
      int t0 = 2 * pp + (lg >> 1); if (t0 > 26) t0 = 26;
      int dd = t0 / 9 - 1, dh = (t0 / 3) % 3 - 1, dw = t0 % 3 - 1;
      int q = lg & 1;
      int zd = wvd + 1 + dd;
      int base = (q * 432 + (zd * 6 + (1 + dh + jbase)) * 18 + 1 + l15 + dw) * 8;
#pragma unroll
      for (int j = 0; j < 2; ++j) {
        short8 B = *(const short8*)(xs + base + j * (18 * 8));
        acc[0][j] = __builtin_amdgcn_mfma_f32_16x16x32_bf16(A0, B, acc[0][j], 0, 0, 0);
        if (CO_TILES == 2)
          acc[1][j] = __builtin_amdgcn_mfma_f32_16x16x32_bf16(A1, B, acc[1][j], 0, 0, 0);
      }
    }
  } else if constexpr (VARIANT == 0) {
    // stride-1 conv: s=b+j row-sharing; fused BN; tile 2x4x16.
    __shared__ unsigned short xs[4 * 432 * 8];
    const int nch = CIP >> 5;
#pragma unroll 1
    for (int ch = 0; ch < nch; ++ch) {
      int c0 = ch << 5;
      const unsigned short* src; int Cs, cl_; bool useBN;
      if (c0 < CA){ src = inA; Cs = CA; cl_ = c0; useBN = (scA != nullptr); }
      else        { src = inB; Cs = CB; cl_ = c0 - CA; useBN = false; }
      const unsigned short* sb = src + (long)n * Cs * spin;
      __syncthreads();
      for (int idx = tid; idx < 4 * 432; idx += TPB) {
        int q = idx / 432, pt = idx - q * 432;
        int zw = pt % 18; int zt = pt / 18; int zh = zt % 6; int zd = zt / 6;
        int gd = d0 + zd - 1, gh = h0 + zh - 1, gw = w0 + zw - 1;
        ushort8 v = (ushort8){0,0,0,0,0,0,0,0};
        if ((unsigned)gd < (unsigned)G && (unsigned)gh < (unsigned)G && (unsigned)gw < (unsigned)G) {
          v = *(const ushort8*)(sb + (((long)gd * G + gh) * G + gw) * Cs + cl_ + q * 8);
          if (useBN) v = bnApply8(v, scA, shA, cl_ + q * 8);
        }
        *(ushort8*)(xs + (q * 432 + pt) * 8) = v;
      }
      __syncthreads();
#pragma unroll 1
      for (int a = 0; a < 3; ++a) {
        int zd = wvd + a;
        short8 A0[3][3], A1[3][3];
#pragma unroll
        for (int b = 0; b < 3; ++b)
#pragma unroll
          for (int c = 0; c < 3; ++c) {
            int tap = (a * 3 + b) * 3 + c;
            const unsigned short* ap = wb + ((long)tap * COP + co0 + l15) * CIP + c0 + lg * 8;
            A0[b][c] = *(const short8*)ap;
            if (CO_TILES == 2) A1[b][c] = *(const short8*)(ap + 16 * CIP);
          }
#pragma unroll
        for (int sl = 0; sl < 4; ++sl) {
          int sg = jbase + sl;
          int rb = (lg * 432 + (zd * 6 + sg) * 18 + l15) * 8;
          short8 B0 = *(const short8*)(xs + rb);
          short8 B1 = *(const short8*)(xs + rb + 8);
          short8 B2 = *(const short8*)(xs + rb + 16);
#pragma unroll
          for (int b = 0; b < 3; ++b) {
            int j = sl - b;
            if (j >= 0 && j < 2) {
              acc[0][j] = __builtin_amdgcn_mfma_f32_16x16x32_bf16(A0[b][0], B0, acc[0][j], 0, 0, 0);
              acc[0][j] = __builtin_amdgcn_mfma_f32_16x16x32_bf16(A0[b][1], B1, acc[0][j], 0, 0, 0);
              acc[0][j] = __builtin_amdgcn_mfma_f32_16x16x32_bf16(A0[b][2], B2, acc[0][j], 0, 0, 0);
              if (CO_TILES == 2) {
                acc[1][j] = __builtin_amdgcn_mfma_f32_16x16x32_bf16(A1[b][0], B0, acc[1][j], 0, 0, 0);
                acc[1][j] = __builtin_amdgcn_mfma_f32_16x16x32_bf16(A1[b][1], B1, acc[1][j], 0, 0, 0);
                acc[1][j] = __builtin_amdgcn_mfma_f32_16x16x32_bf16(A1[b][2], B2, acc[1][j], 0, 0, 0);
              }
            }
          }
        }
      }
    }
  } else {
    // VARIANT 2: stride-2 conv, direct-global B (inputs pre-normalized).
    const int nch = CIP >> 5;
#pragma unroll 1
    for (int ch = 0; ch < nch; ++ch) {
      int c0 = ch << 5;
      const unsigned short* src; int Cs, cl_;
      if (c0 < CA){ src = inA; Cs = CA; cl_ = c0; } else { src = inB; Cs = CB; cl_ = c0 - CA; }
      const unsigned short* sb = src + (long)n * Cs * spin;
#pragma unroll 1
      for (int a = 0; a < 3; ++a) {
        int gd = 2 * (d0 + wv) + a - 1;
        bool vd = (unsigned)gd < (unsigned)Gin;
#pragma unroll 1
        for (int b = 0; b < 3; ++b) {
#pragma unroll
          for (int c = 0; c < 3; ++c) {
            int tap = (a * 3 + b) * 3 + c;
            const unsigned short* ap = wb + ((long)tap * COP + co0 + l15) * CIP + c0 + lg * 8;
            short8 A0 = *(const short8*)ap;
            short8 A1;
            if (CO_TILES == 2) A1 = *(const short8*)(ap + 16 * CIP);
            int gw = 2 * (w0 + l15) + c - 1;
            bool vdw = vd && ((unsigned)gw < (unsigned)Gin);
#pragma unroll
            for (int j = 0; j < JR; ++j) {
              int gh = 2 * (h0 + j) + b - 1;
              short8 B = (short8){0,0,0,0,0,0,0,0};
              if (vdw && (unsigned)gh < (unsigned)Gin)
                B = *(const short8*)(sb + (((long)gd * Gin + gh) * Gin + gw) * Cs + cl_ + lg * 8);
              acc[0][j] = __builtin_amdgcn_mfma_f32_16x16x32_bf16(A0, B, acc[0][j], 0, 0, 0);
              if (CO_TILES == 2)
                acc[1][j] = __builtin_amdgcn_mfma_f32_16x16x32_bf16(A1, B, acc[1][j], 0, 0, 0);
            }
          }
        }
      }
    }
  }

  // ---- store ----
  const long spo = (long)G * G * G;
#pragma unroll
  for (int j = 0; j < JR; ++j) {
    long pt;
    if constexpr (VARIANT == 0)
      pt = ((long)(d0 + wvd) * G + (h0 + jbase + j)) * G + (w0 + l15);
    else
      pt = ((long)(d0 + wv) * G + (h0 + j)) * G + (w0 + l15);
    if constexpr (!FOUT) {
      unsigned short* outp = (unsigned short*)outv;
#pragma unroll
      for (int ct = 0; ct < CO_TILES; ++ct) {
        ushort4v pk;
#pragma unroll
        for (int r = 0; r < 4; ++r) pk[r] = f2b(acc[ct][j][r]);
        *(ushort4v*)(outp + ((long)n * spo + pt) * Cout + co0 + ct * 16 + lg * 4) = pk;
      }
    } else {
      float* outp = (float*)outv;
#pragma unroll
      for (int ct = 0; ct < CO_TILES; ++ct)
#pragma unroll
        for (int r = 0; r < 4; ++r) {
          int co = co0 + ct * 16 + lg * 4 + r;
          if (co < Cout) outp[((long)(n * Cout + co)) * spo + pt] = acc[ct][j][r];
        }
    }
  }
}

// ---------------- BN stats stage 1 (channels-last, raw tensor) ----------------
__global__ void bn_stats1_cl(const unsigned short* __restrict__ x, float* __restrict__ part,
                             long npts, int C, int lC, int K){
  int chunk = blockIdx.x, tid = threadIdx.x;
  int c = tid & (C - 1); int pr = tid >> lC; int PR = TPB >> lC;
  float s = 0.f, q = 0.f;
  for (long p = (long)chunk * PR + pr; p < npts; p += (long)K * PR) {
    float f = b2f(x[p * C + c]); s += f; q += f * f;
  }
  __shared__ float shs[TPB], shq[TPB];
  shs[tid] = s; shq[tid] = q;
  __syncthreads();
  for (int off = TPB / 2; off >= C; off >>= 1) {
    if (tid < off) { shs[tid] += shs[tid + off]; shq[tid] += shq[tid + off]; }
    __syncthreads();
  }
  if (tid < C) { part[((long)tid * K + chunk) * 2] = shs[tid]; part[((long)tid * K + chunk) * 2 + 1] = shq[tid]; }
}

// ---------------- BN stats stage 2 -> scale/shift ----------------
__global__ void bn_stats2_k(const float* __restrict__ part, const float* __restrict__ g,
                            const float* __restrict__ b, float* __restrict__ scale,
                            float* __restrict__ shift, int C, int K, float inv_cnt) {
  int c = blockIdx.x * blockDim.x + threadIdx.x;
  if (c >= C) return;
  float s = 0.f, q = 0.f;
  for (int k = 0; k < K; ++k) { s += part[((long)c * K + k) * 2]; q += part[((long)c * K + k) * 2 + 1]; }
  float m = s * inv_cnt, v = q * inv_cnt - m * m;
  float rs = rsqrtf(v + 1e-5f) * g[c];
  scale[c] = rs;
  shift[c] = b[c] - m * rs;
}

// ---------------- BN apply + ReLU pass (for s1, s2 only) ----------------
__global__ void bn_relu_cl(unsigned short* __restrict__ x, const float* __restrict__ sc,
                           const float* __restrict__ sh, int C, long tot8){
  long i8 = (long)blockIdx.x * TPB + threadIdx.x;
  if (i8 >= tot8) return;
  long e = i8 * 8;
  int c0 = (int)(e & (C - 1));
  ushort8 v = *(ushort8*)(x + e);
  *(ushort8*)(x + e) = bnApply8(v, sc, sh, c0);
}

extern "C" void kernel_launch(void* const* d_in, const int* in_sizes, int n_in,
                              void* d_out, int out_size, void* d_ws, size_t ws_size,
                              hipStream_t stream) {
  const float* x    = (const float*)d_in[0];
  const float* w0   = (const float*)d_in[1];
  const float* g0   = (const float*)d_in[2];
  const float* b0   = (const float*)d_in[3];
  const float* w1   = (const float*)d_in[4];
  const float* g1   = (const float*)d_in[5];
  const float* b1   = (const float*)d_in[6];
  const float* w2   = (const float*)d_in[7];
  const float* g2   = (const float*)d_in[8];
  const float* b2   = (const float*)d_in[9];
  const float* wt2r = (const float*)d_in[10];
  const float* g2r  = (const float*)d_in[11];
  const float* b2r  = (const float*)d_in[12];
  const float* wt1r = (const float*)d_in[13];
  const float* g1r  = (const float*)d_in[14];
  const float* b1r  = (const float*)d_in[15];
  const float* wt0r = (const float*)d_in[16];
  const float* wt2c = (const float*)d_in[17];
  const float* g2c  = (const float*)d_in[18];
  const float* b2c  = (const float*)d_in[19];
  const float* wt1c = (const float*)d_in[20];
  const float* g1c  = (const float*)d_in[21];
  const float* b1c  = (const float*)d_in[22];
  const float* wt0c = (const float*)d_in[23];

  const int N = 2;
  const long sp64 = 262144, sp32 = 32768, sp16 = 4096;
  const int K = 256;  // bn chunks

  // ---- workspace (ushort units), all activations NDHWC bf16 ----
  unsigned short* W = (unsigned short*)d_ws;
  unsigned short* s1   = W;                       // [2*sp64][32]
  unsigned short* s2   = s1  + 16777216;          // [2*sp32][64]
  unsigned short* s4   = s2  + 4194304;           // [2*sp16][128]
  unsigned short* r32  = s4  + 1048576;           // [2*sp32][64]
  unsigned short* c32  = r32 + 4194304;           // [2*sp32][64]
  unsigned short* r64  = c32 + 4194304;           // [2*sp64][32]
  unsigned short* xt   = r64;                     // alias (dead after conv0)
  unsigned short* c64  = r64 + 16777216;          // [2*sp64][64]
  unsigned short* wb0p = c64 + 33554432;          // 14*32*32
  unsigned short* wb1  = wb0p + 14336;            // 27*64*32
  unsigned short* wb2  = wb1  + 55296;            // 27*128*64
  unsigned short* wb2r = wb2  + 221184;           // 27*64*128
  unsigned short* wb2c = wb2r + 221184;
  unsigned short* wb1r = wb2c + 221184;           // 27*32*64
  unsigned short* wb1c = wb1r + 55296;            // 27*64*128
  unsigned short* wbrec= wb1c + 221184;           // 27*16*32
  unsigned short* wbcl = wbrec+ 13824;            // 27*16*96
  float* part = (float*)(wbcl + 41472);
  float* bsc  = part + 128L * K * 2;              // shared (s1, s2)
  float* bsh  = bsc + 128;
  float* sc_s4  = bsh  + 128; float* sh_s4  = sc_s4  + 128;
  float* sc_r32 = sh_s4 + 128; float* sh_r32 = sc_r32 + 128;
  float* sc_c32 = sh_r32+ 128; float* sh_c32 = sc_c32 + 128;
  float* sc_r64 = sh_c32+ 128; float* sh_r64 = sc_r64 + 128;
  float* sc_c64 = sh_r64+ 128; float* sh_c64 = sc_c64 + 128;

  float* out_cl  = (float*)d_out;                 // [2][2][64^3] NCDHW
  float* out_rec = (float*)d_out + 2L * 2 * sp64; // [2][16][64^3]

  // ---- weight repacks ----
  rp_pair<<<cdiv_l(14L*32*32, TPB), TPB, 0, stream>>>(w0, wb0p);
  rp_enc<<<cdiv_l(27L*64*32, TPB), TPB, 0, stream>>>(w1, wb1, 32, 64);
  rp_enc<<<cdiv_l(27L*128*64, TPB), TPB, 0, stream>>>(w2, wb2, 64, 128);
  rp_dec<<<cdiv_l(27L*64*128, TPB), TPB, 0, stream>>>(wt2r, wb2r, 128, 64, 128, 64);
  rp_dec<<<cdiv_l(27L*64*128, TPB), TPB, 0, stream>>>(wt2c, wb2c, 128, 64, 128, 64);
  rp_dec<<<cdiv_l(27L*32*64, TPB), TPB, 0, stream>>>(wt1r, wb1r, 64, 32, 64, 32);
  rp_dec<<<cdiv_l(27L*64*128, TPB), TPB, 0, stream>>>(wt1c, wb1c, 128, 64, 128, 64);
  rp_dec<<<cdiv_l(27L*16*32, TPB), TPB, 0, stream>>>(wt0r, wbrec, 32, 16, 32, 16);
  rp_dec<<<cdiv_l(27L*16*96, TPB), TPB, 0, stream>>>(wt0c, wbcl, 96, 2, 96, 16);

  // ---- x -> NDHWC bf16 ----
  xpose_k<<<2048, TPB, 0, stream>>>(x, xt);

  auto bnStats = [&](unsigned short* t, const float* g, const float* b, int C, int lC,
                     long npts, float* sc, float* sh) {
    bn_stats1_cl<<<K, TPB, 0, stream>>>(t, part, npts, C, lC, K);
    bn_stats2_k<<<1, 128, 0, stream>>>(part, g, b, sc, sh, C, K, 1.f / (float)(npts));
  };
  auto bnFull = [&](unsigned short* t, const float* g, const float* b, int C, int lC, long npts) {
    bnStats(t, g, b, C, lC, npts, bsc, bsh);
    long tot8 = npts * C / 8;
    bn_relu_cl<<<cdiv_l(tot8, TPB), TPB, 0, stream>>>(t, bsc, bsh, C, tot8);
  };

  // grids: V0/PAIRED = 2d x 4h x 16w tiles; V2/tconv = 4d x 4h x 16w
  auto gx0 = [&](int G){ return (unsigned)(N * (G >> 1) * (G >> 2) * (G >> 4)); };
  auto gx  = [&](int G){ return (unsigned)(N * (G >> 2) * (G >> 2) * (G >> 4)); };

  // ---- encoder ----
  mconv<0, 2, true, false><<<dim3(gx0(64), 1), TPB, 0, stream>>>(
      xt, 16, nullptr, 0, nullptr, nullptr, wb0p, s1, N, 32, 32, 32, 64);
  bnFull(s1, g0, b0, 32, 5, 2 * sp64);
  mconv<2, 2, false, false><<<dim3(gx(32), 2), TPB, 0, stream>>>(
      s1, 32, nullptr, 0, nullptr, nullptr, wb1, s2, N, 64, 64, 32, 32);
  bnFull(s2, g1, b1, 64, 6, 2 * sp32);
  mconv<2, 1, false, false><<<dim3(gx(16), 8), TPB, 0, stream>>>(
      s2, 64, nullptr, 0, nullptr, nullptr, wb2, s4, N, 128, 128, 64, 16);
  bnStats(s4, g2, b2, 128, 7, 2 * sp16, sc_s4, sh_s4);

  // ---- level-2 tconvs (16 -> 32), quadrants; BN(s4) fused on load ----
  tconv_quad<2><<<dim3(gx(16), 2, 4), TPB, 0, stream>>>(
      s4, 128, nullptr, 0, sc_s4, sh_s4, wb2r, r32, N, 64, 64, 128, 16);
  bnStats(r32, g2r, b2r, 64, 6, 2 * sp32, sc_r32, sh_r32);
  tconv_quad<2><<<dim3(gx(16), 2, 4), TPB, 0, stream>>>(
      s4, 128, nullptr, 0, sc_s4, sh_s4, wb2c, c32, N, 64, 64, 128, 16);
  bnStats(c32, g2c, b2c, 64, 6, 2 * sp32, sc_c32, sh_c32);

  // ---- level-1 tconvs (32 -> 64), quadrants ----
  tconv_quad<2><<<dim3(gx(32), 1, 4), TPB, 0, stream>>>(
      r32, 64, nullptr, 0, sc_r32, sh_r32, wb1r, r64, N, 32, 32, 64, 32);
  bnStats(r64, g1r, b1r, 32, 5, 2 * sp64, sc_r64, sh_r64);
  tconv_quad<4><<<dim3(gx(32), 1, 4), TPB, 0, stream>>>(
      c32, 64, s2, 64, sc_c32, sh_c32, wb1c, c64, N, 64, 64, 128, 32);
  bnStats(c64, g1c, b1c, 64, 6, 2 * sp64, sc_c64, sh_c64);

  // ---- level-0 stride-1 convs (no BN on output), fused BN on inputs ----
  mconv<0, 1, false, true><<<dim3(gx0(64), 1), TPB, 0, stream>>>(
      r64, 32, nullptr, 0, sc_r64, sh_r64, wbrec, out_rec, N, 16, 16, 32, 64);
  mconv<0, 1, false, true><<<dim3(gx0(64), 1), TPB, 0, stream>>>(
      c64, 64, s1, 32, sc_c64, sh_c64, wbcl, out_cl, N, 2, 16, 96, 64);
}

// Round 13
// 1039.182 us; speedup vs baseline: 1.0352x; 1.0352x over previous
//
#include <hip/hip_runtime.h>
#include <hip/hip_bf16.h>

// ---------------------------------------------------------------------------
// UNet3D dense forward, round 13: revert to R10 (best, 1.040ms) +
//  - tconv_quad: double-buffered LDS, ONE barrier per ci-chunk (stage chunk
//    ch+1 into buf B issued before MFMA of chunk ch from buf A).
//  - conv2: CO_TILES=1, y=8 (256 workgroups; R10's 128 left half GPU idle).
//  - V0 stride-1 convs: R10 exact (2d x 8h x 16w, 2-barrier staging).
// ---------------------------------------------------------------------------

using bf16 = __hip_bfloat16;
using ushort4v = __attribute__((ext_vector_type(4))) unsigned short;
using ushort8  = __attribute__((ext_vector_type(8))) unsigned short;
using short8   = __attribute__((ext_vector_type(8))) short;
using f32x4    = __attribute__((ext_vector_type(4))) float;
using float4v  = __attribute__((ext_vector_type(4))) float;

#define TPB 256

static inline int cdiv_l(long a, int b){ return (int)((a + b - 1) / b); }

__device__ __forceinline__ float b2f(unsigned short u){
  union { unsigned int i; float f; } v; v.i = ((unsigned int)u) << 16; return v.f;
}
__device__ __forceinline__ unsigned short f2b(float f){
  union { bf16 h; unsigned short u; } v; v.h = __float2bfloat16(f); return v.u;
}
// BN+ReLU on 8 packed bf16 channels starting at channel c (8-aligned).
__device__ __forceinline__ ushort8 bnApply8(ushort8 v, const float* sc, const float* sh, int c){
  float4v s0 = *(const float4v*)(sc + c), s1v = *(const float4v*)(sc + c + 4);
  float4v h0 = *(const float4v*)(sh + c), h1v = *(const float4v*)(sh + c + 4);
  ushort8 r;
#pragma unroll
  for (int j = 0; j < 4; ++j){ float y = b2f(v[j]) * s0[j] + h0[j]; r[j] = f2b(y > 0.f ? y : 0.f); }
#pragma unroll
  for (int j = 0; j < 4; ++j){ float y = b2f(v[j+4]) * s1v[j] + h1v[j]; r[j+4] = f2b(y > 0.f ? y : 0.f); }
  return r;
}

// ---------------- weight repacks (bf16) ----------------
__global__ void rp_enc(const float* __restrict__ w, unsigned short* __restrict__ wb,
                       int Cin, int Cout){
  int idx = blockIdx.x * TPB + threadIdx.x;
  int tot = 27 * Cout * Cin; if (idx >= tot) return;
  int ci = idx % Cin; int t = idx / Cin; int co = t % Cout; int tap = t / Cout;
  wb[idx] = f2b(w[((long)co * Cin + ci) * 27 + tap]);
}
__global__ void rp_dec(const float* __restrict__ w, unsigned short* __restrict__ wb,
                       int Cin, int Cout, int CIP, int COP){
  int idx = blockIdx.x * TPB + threadIdx.x;
  int tot = 27 * COP * CIP; if (idx >= tot) return;
  int ci = idx % CIP; int t = idx / CIP; int co = t % COP; int tap = t / COP;
  float v = (ci < Cin && co < Cout) ? w[((long)tap * Cin + ci) * Cout + co] : 0.f;
  wb[idx] = f2b(v);
}
// conv0 tap-paired: [pp<14][co<32][k<32]
__global__ void rp_pair(const float* __restrict__ w, unsigned short* __restrict__ wb){
  int idx = blockIdx.x * TPB + threadIdx.x;
  int tot = 14 * 32 * 32; if (idx >= tot) return;
  int k = idx & 31; int t = idx >> 5; int co = t & 31; int pp = t >> 5;
  int tap = pp * 2 + (k >> 4); int ci = k & 15;
  float v = (tap < 27) ? w[((long)co * 16 + ci) * 27 + tap] : 0.f;
  wb[idx] = f2b(v);
}

// ---------------- x transpose: NCDHW fp32 -> NDHWC bf16 (C=16) ----------------
__global__ void xpose_k(const float* __restrict__ x, unsigned short* __restrict__ xt){
  __shared__ float l[16][257];
  int t = threadIdx.x;
  long p0 = (long)blockIdx.x * 256;
  int n = (int)(p0 >> 18);
  long off = p0 & 262143;
  const float* xb = x + ((long)n * 16) * 262144 + off;
#pragma unroll
  for (int c = 0; c < 16; ++c) l[c][t] = xb[(long)c * 262144 + t];
  __syncthreads();
  ushort8 u0, u1;
#pragma unroll
  for (int k = 0; k < 8; ++k){ u0[k] = f2b(l[k][t]); u1[k] = f2b(l[k + 8][t]); }
  unsigned short* o = xt + (p0 + t) * 16;
  *(ushort8*)o = u0; *(ushort8*)(o + 8) = u1;
}

// ---------------- quadrant stride-2 tconv, double-buffered LDS -------------
// grid.z = quad (pd,ph); both w-parities per thread. One barrier per ci-chunk:
// stage chunk ch+1 into buf^1 (issued before MFMA), compute chunk ch from buf.
template <int CO_TILES>
__global__ __launch_bounds__(TPB, 2) void tconv_quad(
    const unsigned short* __restrict__ inA, int CA,
    const unsigned short* __restrict__ inB, int CB,
    const float* __restrict__ scA, const float* __restrict__ shA,
    const unsigned short* __restrict__ wb,
    unsigned short* __restrict__ out,
    int N, int Cout, int COP, int CIP, int G) {
  __shared__ unsigned short xs[2][4 * 432 * 8];
  const int tid = threadIdx.x, wv = tid >> 6, l = tid & 63, l15 = l & 15, lg = l >> 4;
  int ntW = G >> 4, ntH = G >> 2, ntD = G >> 2;
  int bx = blockIdx.x;
  int w0 = (bx % ntW) << 4; bx /= ntW;
  int h0 = (bx % ntH) << 2; bx /= ntH;
  int d0 = (bx % ntD) << 2; int n = bx / ntD;
  const int co0 = blockIdx.y * (16 * CO_TILES);
  const int quad = blockIdx.z;
  const int pd = (quad >> 1) & 1, ph = quad & 1;
  const long spin = (long)G * G * G;

  int nkd, kd_[2], dd_[2], nkh, kh_[2], dh_[2];
  if (pd){ nkd=1; kd_[0]=1; dd_[0]=0; } else { nkd=2; kd_[0]=0; dd_[0]=-1; kd_[1]=2; dd_[1]=0; }
  if (ph){ nkh=1; kh_[0]=1; dh_[0]=0; } else { nkh=2; kh_[0]=0; dh_[0]=-1; kh_[1]=2; dh_[1]=0; }

  f32x4 acc[CO_TILES][4][2];
#pragma unroll
  for (int ct = 0; ct < CO_TILES; ++ct)
#pragma unroll
    for (int j = 0; j < 4; ++j)
#pragma unroll
      for (int p = 0; p < 2; ++p) acc[ct][j][p] = (f32x4){0.f, 0.f, 0.f, 0.f};

  auto stage = [&](int ch, int buf) {
    int c0 = ch << 5;
    const unsigned short* src; int Cs, cl_; bool useBN;
    if (c0 < CA){ src = inA; Cs = CA; cl_ = c0; useBN = (scA != nullptr); }
    else        { src = inB; Cs = CB; cl_ = c0 - CA; useBN = false; }
    const unsigned short* sb = src + (long)n * Cs * spin;
    unsigned short* xb = &xs[buf][0];
    for (int idx = tid; idx < 4 * 425; idx += TPB) {
      int q = idx / 425, pt = idx - q * 425;
      int zw = pt % 17; int zt = pt / 17; int zh = zt % 5; int zd = zt / 5;
      int gd = d0 + zd - 1, gh = h0 + zh - 1, gw = w0 + zw - 1;
      ushort8 v = (ushort8){0,0,0,0,0,0,0,0};
      if ((unsigned)gd < (unsigned)G && (unsigned)gh < (unsigned)G && (unsigned)gw < (unsigned)G) {
        v = *(const ushort8*)(sb + (((long)gd * G + gh) * G + gw) * Cs + cl_ + q * 8);
        if (useBN) v = bnApply8(v, scA, shA, cl_ + q * 8);
      }
      *(ushort8*)(xb + (q * 432 + pt) * 8) = v;
    }
  };

  const int nch = CIP >> 5;
  stage(0, 0);
  __syncthreads();
#pragma unroll 1
  for (int ch = 0; ch < nch; ++ch) {
    int cur = ch & 1;
    int c0 = ch << 5;
    if (ch + 1 < nch) stage(ch + 1, cur ^ 1);   // issued before MFMA; lands before next barrier
    const unsigned short* xr = &xs[cur][0];
#pragma unroll 1
    for (int a = 0; a < nkd; ++a) {
      int zd = wv + 1 + dd_[a];
#pragma unroll 1
      for (int b = 0; b < nkh; ++b) {
        int tapb = (kd_[a] * 3 + kh_[b]) * 3;
        const unsigned short* ap = wb + ((long)tapb * COP + co0 + l15) * CIP + c0 + lg * 8;
        long tstride = (long)COP * CIP;
        short8 Ak0[CO_TILES], Ak1[CO_TILES], Ak2[CO_TILES];
#pragma unroll
        for (int ct = 0; ct < CO_TILES; ++ct) {
          Ak0[ct] = *(const short8*)(ap + ct * 16 * CIP);
          Ak1[ct] = *(const short8*)(ap + tstride + ct * 16 * CIP);
          Ak2[ct] = *(const short8*)(ap + 2 * tstride + ct * 16 * CIP);
        }
        int zh0 = 1 + dh_[b];
#pragma unroll
        for (int j = 0; j < 4; ++j) {
          int basept = (zd * 5 + (j + zh0)) * 17 + l15;
          short8 Bm = *(const short8*)(xr + (lg * 432 + basept) * 8);
          short8 B0 = *(const short8*)(xr + (lg * 432 + basept + 1) * 8);
#pragma unroll
          for (int ct = 0; ct < CO_TILES; ++ct) {
            acc[ct][j][0] = __builtin_amdgcn_mfma_f32_16x16x32_bf16(Ak0[ct], Bm, acc[ct][j][0], 0, 0, 0);
            acc[ct][j][0] = __builtin_amdgcn_mfma_f32_16x16x32_bf16(Ak2[ct], B0, acc[ct][j][0], 0, 0, 0);
            acc[ct][j][1] = __builtin_amdgcn_mfma_f32_16x16x32_bf16(Ak1[ct], B0, acc[ct][j][1], 0, 0, 0);
          }
        }
      }
    }
    __syncthreads();
  }

  // ---- dense store ----
  int Gout = 2 * G; long spo = (long)Gout * Gout * Gout;
  int od = 2 * (d0 + wv) + pd;
#pragma unroll
  for (int j = 0; j < 4; ++j) {
    int oh = 2 * (h0 + j) + ph;
#pragma unroll
    for (int p = 0; p < 2; ++p) {
      int ow = 2 * (w0 + l15) + p;
      long pt = ((long)od * Gout + oh) * Gout + ow;
#pragma unroll
      for (int ct = 0; ct < CO_TILES; ++ct) {
        ushort4v pk;
#pragma unroll
        for (int r = 0; r < 4; ++r) pk[r] = f2b(acc[ct][j][p][r]);
        *(ushort4v*)(out + ((long)n * spo + pt) * Cout + co0 + ct * 16 + lg * 4) = pk;
      }
    }
  }
}

// ---------------- unified NDHWC MFMA conv ----------------
// VARIANT 0 / PAIRED: stride-1 conv, LDS-staged, tile 2d x 8h x 16w.
//   wave wv: wvd = wv&1 (d-slice), jh = wv>>1 (h-half, 4 j-rows each).
// VARIANT 2: stride-2 conv, direct-global B, tile 4d x 4h x 16w.
template <int VARIANT, int CO_TILES, bool PAIRED, bool FOUT>
__global__ __launch_bounds__(TPB) void mconv(
    const unsigned short* __restrict__ inA, int CA,
    const unsigned short* __restrict__ inB, int CB,
    const float* __restrict__ scA, const float* __restrict__ shA,
    const unsigned short* __restrict__ wb,
    void* __restrict__ outv,
    int N, int Cout, int COP, int CIP, int G) {
  const int tid = threadIdx.x, wv = tid >> 6, l = tid & 63, l15 = l & 15, lg = l >> 4;
  int bx = blockIdx.x;
  int w0, h0, d0, n;
  int wvd = wv & 1, jh = wv >> 1, jbase = jh * 4;
  if constexpr (VARIANT == 0) {
    int ntW = G >> 4, ntH = G >> 3, ntD = G >> 1;
    w0 = (bx % ntW) << 4; bx /= ntW;
    h0 = (bx % ntH) << 3; bx /= ntH;
    d0 = (bx % ntD) << 1; n = bx / ntD;
  } else {
    int ntW = G >> 4, ntH = G >> 2, ntD = G >> 2;
    w0 = (bx % ntW) << 4; bx /= ntW;
    h0 = (bx % ntH) << 2; bx /= ntH;
    d0 = (bx % ntD) << 2; n = bx / ntD;
  }
  const int co0 = blockIdx.y * (16 * CO_TILES);
  const int Gin = (VARIANT == 2) ? 2 * G : G;
  const long spin = (long)Gin * Gin * Gin;

  f32x4 acc[CO_TILES][4];
#pragma unroll
  for (int ct = 0; ct < CO_TILES; ++ct)
#pragma unroll
    for (int j = 0; j < 4; ++j) acc[ct][j] = (f32x4){0.f, 0.f, 0.f, 0.f};

  if constexpr (PAIRED) {
    // conv0: Cin=16, K packs 2 taps; raw input (no BN).
    __shared__ unsigned short xs[2 * 728 * 8];
    const unsigned short* src = inA + (long)n * 16 * spin;
    for (int idx = tid; idx < 2 * 720; idx += TPB) {
      int q = idx / 720, pt = idx - q * 720;
      int zw = pt % 18; int zt = pt / 18; int zh = zt % 10; int zd = zt / 10;
      int gd = d0 + zd - 1, gh = h0 + zh - 1, gw = w0 + zw - 1;
      ushort8 v = (ushort8){0,0,0,0,0,0,0,0};
      if ((unsigned)gd < (unsigned)G && (unsigned)gh < (unsigned)G && (unsigned)gw < (unsigned)G)
        v = *(const ushort8*)(src + (((long)gd * G + gh) * G + gw) * 16 + q * 8);
      *(ushort8*)(xs + (q * 728 + pt) * 8) = v;
    }
    __syncthreads();
#pragma unroll 1
    for (int pp = 0; pp < 14; ++pp) {
      short8 A0 = *(const short8*)(wb + ((pp * 32 + l15) * 32) + lg * 8);
      short8 A1 = *(const short8*)(wb + ((pp * 32 + 16 + l15) * 32) + lg * 8);
      int t0 = 2 * pp + (lg >> 1); if (t0 > 26) t0 = 26;
      int dd = t0 / 9 - 1, dh = (t0 / 3) % 3 - 1, dw = t0 % 3 - 1;
      int q = lg & 1;
      int zd = wvd + 1 + dd;
      int base = (q * 728 + (zd * 10 + (1 + dh + jbase)) * 18 + 1 + l15 + dw) * 8;
#pragma unroll
      for (int j = 0; j < 4; ++j) {
        short8 B = *(const short8*)(xs + base + j * (18 * 8));
        acc[0][j] = __builtin_amdgcn_mfma_f32_16x16x32_bf16(A0, B, acc[0][j], 0, 0, 0);
        if (CO_TILES == 2)
          acc[1][j] = __builtin_amdgcn_mfma_f32_16x16x32_bf16(A1, B, acc[1][j], 0, 0, 0);
      }
    }
  } else if constexpr (VARIANT == 0) {
    // stride-1 conv: s=b+j row-sharing; fused BN on A-source chunks.
    __shared__ unsigned short xs[4 * 728 * 8];
    const int nch = CIP >> 5;
#pragma unroll 1
    for (int ch = 0; ch < nch; ++ch) {
      int c0 = ch << 5;
      const unsigned short* src; int Cs, cl_; bool useBN;
      if (c0 < CA){ src = inA; Cs = CA; cl_ = c0; useBN = (scA != nullptr); }
      else        { src = inB; Cs = CB; cl_ = c0 - CA; useBN = false; }
      const unsigned short* sb = src + (long)n * Cs * spin;
      __syncthreads();
      for (int idx = tid; idx < 4 * 720; idx += TPB) {
        int q = idx / 720, pt = idx - q * 720;
        int zw = pt % 18; int zt = pt / 18; int zh = zt % 10; int zd = zt / 10;
        int gd = d0 + zd - 1, gh = h0 + zh - 1, gw = w0 + zw - 1;
        ushort8 v = (ushort8){0,0,0,0,0,0,0,0};
        if ((unsigned)gd < (unsigned)G && (unsigned)gh < (unsigned)G && (unsigned)gw < (unsigned)G) {
          v = *(const ushort8*)(sb + (((long)gd * G + gh) * G + gw) * Cs + cl_ + q * 8);
          if (useBN) v = bnApply8(v, scA, shA, cl_ + q * 8);
        }
        *(ushort8*)(xs + (q * 728 + pt) * 8) = v;
      }
      __syncthreads();
#pragma unroll 1
      for (int a = 0; a < 3; ++a) {
        int zd = wvd + a;
        short8 A0[3][3], A1[3][3];
#pragma unroll
        for (int b = 0; b < 3; ++b)
#pragma unroll
          for (int c = 0; c < 3; ++c) {
            int tap = (a * 3 + b) * 3 + c;
            const unsigned short* ap = wb + ((long)tap * COP + co0 + l15) * CIP + c0 + lg * 8;
            A0[b][c] = *(const short8*)ap;
            if (CO_TILES == 2) A1[b][c] = *(const short8*)(ap + 16 * CIP);
          }
#pragma unroll
        for (int sl = 0; sl < 6; ++sl) {
          int sg = jbase + sl;
          int rb = (lg * 728 + (zd * 10 + sg) * 18 + l15) * 8;
          short8 B0 = *(const short8*)(xs + rb);
          short8 B1 = *(const short8*)(xs + rb + 8);
          short8 B2 = *(const short8*)(xs + rb + 16);
#pragma unroll
          for (int b = 0; b < 3; ++b) {
            int j = sl - b;
            if (j >= 0 && j < 4) {
              acc[0][j] = __builtin_amdgcn_mfma_f32_16x16x32_bf16(A0[b][0], B0, acc[0][j], 0, 0, 0);
              acc[0][j] = __builtin_amdgcn_mfma_f32_16x16x32_bf16(A0[b][1], B1, acc[0][j], 0, 0, 0);
              acc[0][j] = __builtin_amdgcn_mfma_f32_16x16x32_bf16(A0[b][2], B2, acc[0][j], 0, 0, 0);
              if (CO_TILES == 2) {
                acc[1][j] = __builtin_amdgcn_mfma_f32_16x16x32_bf16(A1[b][0], B0, acc[1][j], 0, 0, 0);
                acc[1][j] = __builtin_amdgcn_mfma_f32_16x16x32_bf16(A1[b][1], B1, acc[1][j], 0, 0, 0);
                acc[1][j] = __builtin_amdgcn_mfma_f32_16x16x32_bf16(A1[b][2], B2, acc[1][j], 0, 0, 0);
              }
            }
          }
        }
      }
    }
  } else {
    // VARIANT 2: stride-2 conv, direct-global B (inputs pre-normalized).
    const int nch = CIP >> 5;
#pragma unroll 1
    for (int ch = 0; ch < nch; ++ch) {
      int c0 = ch << 5;
      const unsigned short* src; int Cs, cl_;
      if (c0 < CA){ src = inA; Cs = CA; cl_ = c0; } else { src = inB; Cs = CB; cl_ = c0 - CA; }
      const unsigned short* sb = src + (long)n * Cs * spin;
#pragma unroll 1
      for (int a = 0; a < 3; ++a) {
        int gd = 2 * (d0 + wv) + a - 1;
        bool vd = (unsigned)gd < (unsigned)Gin;
#pragma unroll 1
        for (int b = 0; b < 3; ++b) {
#pragma unroll
          for (int c = 0; c < 3; ++c) {
            int tap = (a * 3 + b) * 3 + c;
            const unsigned short* ap = wb + ((long)tap * COP + co0 + l15) * CIP + c0 + lg * 8;
            short8 A0 = *(const short8*)ap;
            short8 A1;
            if (CO_TILES == 2) A1 = *(const short8*)(ap + 16 * CIP);
            int gw = 2 * (w0 + l15) + c - 1;
            bool vdw = vd && ((unsigned)gw < (unsigned)Gin);
#pragma unroll
            for (int j = 0; j < 4; ++j) {
              int gh = 2 * (h0 + j) + b - 1;
              short8 B = (short8){0,0,0,0,0,0,0,0};
              if (vdw && (unsigned)gh < (unsigned)Gin)
                B = *(const short8*)(sb + (((long)gd * Gin + gh) * Gin + gw) * Cs + cl_ + lg * 8);
              acc[0][j] = __builtin_amdgcn_mfma_f32_16x16x32_bf16(A0, B, acc[0][j], 0, 0, 0);
              if (CO_TILES == 2)
                acc[1][j] = __builtin_amdgcn_mfma_f32_16x16x32_bf16(A1, B, acc[1][j], 0, 0, 0);
            }
          }
        }
      }
    }
  }

  // ---- store ----
  const long spo = (long)G * G * G;
#pragma unroll
  for (int j = 0; j < 4; ++j) {
    long pt;
    if constexpr (VARIANT == 0)
      pt = ((long)(d0 + wvd) * G + (h0 + jbase + j)) * G + (w0 + l15);
    else
      pt = ((long)(d0 + wv) * G + (h0 + j)) * G + (w0 + l15);
    if constexpr (!FOUT) {
      unsigned short* outp = (unsigned short*)outv;
#pragma unroll
      for (int ct = 0; ct < CO_TILES; ++ct) {
        ushort4v pk;
#pragma unroll
        for (int r = 0; r < 4; ++r) pk[r] = f2b(acc[ct][j][r]);
        *(ushort4v*)(outp + ((long)n * spo + pt) * Cout + co0 + ct * 16 + lg * 4) = pk;
      }
    } else {
      float* outp = (float*)outv;
#pragma unroll
      for (int ct = 0; ct < CO_TILES; ++ct)
#pragma unroll
        for (int r = 0; r < 4; ++r) {
          int co = co0 + ct * 16 + lg * 4 + r;
          if (co < Cout) outp[((long)(n * Cout + co)) * spo + pt] = acc[ct][j][r];
        }
    }
  }
}

// ---------------- BN stats stage 1 (channels-last, raw tensor) ----------------
__global__ void bn_stats1_cl(const unsigned short* __restrict__ x, float* __restrict__ part,
                             long npts, int C, int lC, int K){
  int chunk = blockIdx.x, tid = threadIdx.x;
  int c = tid & (C - 1); int pr = tid >> lC; int PR = TPB >> lC;
  float s = 0.f, q = 0.f;
  for (long p = (long)chunk * PR + pr; p < npts; p += (long)K * PR) {
    float f = b2f(x[p * C + c]); s += f; q += f * f;
  }
  __shared__ float shs[TPB], shq[TPB];
  shs[tid] = s; shq[tid] = q;
  __syncthreads();
  for (int off = TPB / 2; off >= C; off >>= 1) {
    if (tid < off) { shs[tid] += shs[tid + off]; shq[tid] += shq[tid + off]; }
    __syncthreads();
  }
  if (tid < C) { part[((long)tid * K + chunk) * 2] = shs[tid]; part[((long)tid * K + chunk) * 2 + 1] = shq[tid]; }
}

// ---------------- BN stats stage 2 -> scale/shift ----------------
__global__ void bn_stats2_k(const float* __restrict__ part, const float* __restrict__ g,
                            const float* __restrict__ b, float* __restrict__ scale,
                            float* __restrict__ shift, int C, int K, float inv_cnt) {
  int c = blockIdx.x * blockDim.x + threadIdx.x;
  if (c >= C) return;
  float s = 0.f, q = 0.f;
  for (int k = 0; k < K; ++k) { s += part[((long)c * K + k) * 2]; q += part[((long)c * K + k) * 2 + 1]; }
  float m = s * inv_cnt, v = q * inv_cnt - m * m;
  float rs = rsqrtf(v + 1e-5f) * g[c];
  scale[c] = rs;
  shift[c] = b[c] - m * rs;
}

// ---------------- BN apply + ReLU pass (for s1, s2 only) ----------------
__global__ void bn_relu_cl(unsigned short* __restrict__ x, const float* __restrict__ sc,
                           const float* __restrict__ sh, int C, long tot8){
  long i8 = (long)blockIdx.x * TPB + threadIdx.x;
  if (i8 >= tot8) return;
  long e = i8 * 8;
  int c0 = (int)(e & (C - 1));
  ushort8 v = *(ushort8*)(x + e);
  *(ushort8*)(x + e) = bnApply8(v, sc, sh, c0);
}

extern "C" void kernel_launch(void* const* d_in, const int* in_sizes, int n_in,
                              void* d_out, int out_size, void* d_ws, size_t ws_size,
                              hipStream_t stream) {
  const float* x    = (const float*)d_in[0];
  const float* w0   = (const float*)d_in[1];
  const float* g0   = (const float*)d_in[2];
  const float* b0   = (const float*)d_in[3];
  const float* w1   = (const float*)d_in[4];
  const float* g1   = (const float*)d_in[5];
  const float* b1   = (const float*)d_in[6];
  const float* w2   = (const float*)d_in[7];
  const float* g2   = (const float*)d_in[8];
  const float* b2   = (const float*)d_in[9];
  const float* wt2r = (const float*)d_in[10];
  const float* g2r  = (const float*)d_in[11];
  const float* b2r  = (const float*)d_in[12];
  const float* wt1r = (const float*)d_in[13];
  const float* g1r  = (const float*)d_in[14];
  const float* b1r  = (const float*)d_in[15];
  const float* wt0r = (const float*)d_in[16];
  const float* wt2c = (const float*)d_in[17];
  const float* g2c  = (const float*)d_in[18];
  const float* b2c  = (const float*)d_in[19];
  const float* wt1c = (const float*)d_in[20];
  const float* g1c  = (const float*)d_in[21];
  const float* b1c  = (const float*)d_in[22];
  const float* wt0c = (const float*)d_in[23];

  const int N = 2;
  const long sp64 = 262144, sp32 = 32768, sp16 = 4096;
  const int K = 256;  // bn chunks

  // ---- workspace (ushort units), all activations NDHWC bf16 ----
  unsigned short* W = (unsigned short*)d_ws;
  unsigned short* s1   = W;                       // [2*sp64][32]
  unsigned short* s2   = s1  + 16777216;          // [2*sp32][64]
  unsigned short* s4   = s2  + 4194304;           // [2*sp16][128]
  unsigned short* r32  = s4  + 1048576;           // [2*sp32][64]
  unsigned short* c32  = r32 + 4194304;           // [2*sp32][64]
  unsigned short* r64  = c32 + 4194304;           // [2*sp64][32]
  unsigned short* xt   = r64;                     // alias (dead after conv0)
  unsigned short* c64  = r64 + 16777216;          // [2*sp64][64]
  unsigned short* wb0p = c64 + 33554432;          // 14*32*32
  unsigned short* wb1  = wb0p + 14336;            // 27*64*32
  unsigned short* wb2  = wb1  + 55296;            // 27*128*64
  unsigned short* wb2r = wb2  + 221184;           // 27*64*128
  unsigned short* wb2c = wb2r + 221184;
  unsigned short* wb1r = wb2c + 221184;           // 27*32*64
  unsigned short* wb1c = wb1r + 55296;            // 27*64*128
  unsigned short* wbrec= wb1c + 221184;           // 27*16*32
  unsigned short* wbcl = wbrec+ 13824;            // 27*16*96
  float* part = (float*)(wbcl + 41472);
  float* bsc  = part + 128L * K * 2;              // shared (s1, s2)
  float* bsh  = bsc + 128;
  float* sc_s4  = bsh  + 128; float* sh_s4  = sc_s4  + 128;
  float* sc_r32 = sh_s4 + 128; float* sh_r32 = sc_r32 + 128;
  float* sc_c32 = sh_r32+ 128; float* sh_c32 = sc_c32 + 128;
  float* sc_r64 = sh_c32+ 128; float* sh_r64 = sc_r64 + 128;
  float* sc_c64 = sh_r64+ 128; float* sh_c64 = sc_c64 + 128;

  float* out_cl  = (float*)d_out;                 // [2][2][64^3] NCDHW
  float* out_rec = (float*)d_out + 2L * 2 * sp64; // [2][16][64^3]

  // ---- weight repacks ----
  rp_pair<<<cdiv_l(14L*32*32, TPB), TPB, 0, stream>>>(w0, wb0p);
  rp_enc<<<cdiv_l(27L*64*32, TPB), TPB, 0, stream>>>(w1, wb1, 32, 64);
  rp_enc<<<cdiv_l(27L*128*64, TPB), TPB, 0, stream>>>(w2, wb2, 64, 128);
  rp_dec<<<cdiv_l(27L*64*128, TPB), TPB, 0, stream>>>(wt2r, wb2r, 128, 64, 128, 64);
  rp_dec<<<cdiv_l(27L*64*128, TPB), TPB, 0, stream>>>(wt2c, wb2c, 128, 64, 128, 64);
  rp_dec<<<cdiv_l(27L*32*64, TPB), TPB, 0, stream>>>(wt1r, wb1r, 64, 32, 64, 32);
  rp_dec<<<cdiv_l(27L*64*128, TPB), TPB, 0, stream>>>(wt1c, wb1c, 128, 64, 128, 64);
  rp_dec<<<cdiv_l(27L*16*32, TPB), TPB, 0, stream>>>(wt0r, wbrec, 32, 16, 32, 16);
  rp_dec<<<cdiv_l(27L*16*96, TPB), TPB, 0, stream>>>(wt0c, wbcl, 96, 2, 96, 16);

  // ---- x -> NDHWC bf16 ----
  xpose_k<<<2048, TPB, 0, stream>>>(x, xt);

  auto bnStats = [&](unsigned short* t, const float* g, const float* b, int C, int lC,
                     long npts, float* sc, float* sh) {
    bn_stats1_cl<<<K, TPB, 0, stream>>>(t, part, npts, C, lC, K);
    bn_stats2_k<<<1, 128, 0, stream>>>(part, g, b, sc, sh, C, K, 1.f / (float)(npts));
  };
  auto bnFull = [&](unsigned short* t, const float* g, const float* b, int C, int lC, long npts) {
    bnStats(t, g, b, C, lC, npts, bsc, bsh);
    long tot8 = npts * C / 8;
    bn_relu_cl<<<cdiv_l(tot8, TPB), TPB, 0, stream>>>(t, bsc, bsh, C, tot8);
  };

  // grids: V0/PAIRED = 2d x 8h x 16w tiles; V2/tconv = 4d x 4h x 16w
  auto gx0 = [&](int G){ return (unsigned)(N * (G >> 1) * (G >> 3) * (G >> 4)); };
  auto gx  = [&](int G){ return (unsigned)(N * (G >> 2) * (G >> 2) * (G >> 4)); };

  // ---- encoder ----
  mconv<0, 2, true, false><<<dim3(gx0(64), 1), TPB, 0, stream>>>(
      xt, 16, nullptr, 0, nullptr, nullptr, wb0p, s1, N, 32, 32, 32, 64);
  bnFull(s1, g0, b0, 32, 5, 2 * sp64);
  mconv<2, 2, false, false><<<dim3(gx(32), 2), TPB, 0, stream>>>(
      s1, 32, nullptr, 0, nullptr, nullptr, wb1, s2, N, 64, 64, 32, 32);
  bnFull(s2, g1, b1, 64, 6, 2 * sp32);
  mconv<2, 1, false, false><<<dim3(gx(16), 8), TPB, 0, stream>>>(
      s2, 64, nullptr, 0, nullptr, nullptr, wb2, s4, N, 128, 128, 64, 16);
  bnStats(s4, g2, b2, 128, 7, 2 * sp16, sc_s4, sh_s4);

  // ---- level-2 tconvs (16 -> 32), quadrants; BN(s4) fused on load ----
  tconv_quad<2><<<dim3(gx(16), 2, 4), TPB, 0, stream>>>(
      s4, 128, nullptr, 0, sc_s4, sh_s4, wb2r, r32, N, 64, 64, 128, 16);
  bnStats(r32, g2r, b2r, 64, 6, 2 * sp32, sc_r32, sh_r32);
  tconv_quad<2><<<dim3(gx(16), 2, 4), TPB, 0, stream>>>(
      s4, 128, nullptr, 0, sc_s4, sh_s4, wb2c, c32, N, 64, 64, 128, 16);
  bnStats(c32, g2c, b2c, 64, 6, 2 * sp32, sc_c32, sh_c32);

  // ---- level-1 tconvs (32 -> 64), quadrants ----
  tconv_quad<2><<<dim3(gx(32), 1, 4), TPB, 0, stream>>>(
      r32, 64, nullptr, 0, sc_r32, sh_r32, wb1r, r64, N, 32, 32, 64, 32);
  bnStats(r64, g1r, b1r, 32, 5, 2 * sp64, sc_r64, sh_r64);
  tconv_quad<4><<<dim3(gx(32), 1, 4), TPB, 0, stream>>>(
      c32, 64, s2, 64, sc_c32, sh_c32, wb1c, c64, N, 64, 64, 128, 32);
  bnStats(c64, g1c, b1c, 64, 6, 2 * sp64, sc_c64, sh_c64);

  // ---- level-0 stride-1 convs (no BN on output), fused BN on inputs ----
  mconv<0, 1, false, true><<<dim3(gx0(64), 1), TPB, 0, stream>>>(
      r64, 32, nullptr, 0, sc_r64, sh_r64, wbrec, out_rec, N, 16, 16, 32, 64);
  mconv<0, 1, false, true><<<dim3(gx0(64), 1), TPB, 0, stream>>>(
      c64, 64, s1, 32, sc_c64, sh_c64, wbcl, out_cl, N, 2, 16, 96, 64);
}

// Round 14
// 569.588 us; speedup vs baseline: 1.8886x; 1.8244x over previous
//
#include <hip/hip_runtime.h>
#include <hip/hip_bf16.h>

// ---------------------------------------------------------------------------
// UNet3D dense forward, round 14: R13 compute kernels + inter-kernel overhead
// reduction:
//  - BN stats fused into producers (deterministic in-block reduce -> per-block
//    per-channel partials; tiny bn_stats2b reduces). 7 full-tensor stat reads
//    and 6 launches removed.
//  - tconv2r+tconv2c merged into one dual-head kernel (s4 staged once).
//  - 9 weight-repack kernels merged into 1.
// ---------------------------------------------------------------------------

using bf16 = __hip_bfloat16;
using ushort4v = __attribute__((ext_vector_type(4))) unsigned short;
using ushort8  = __attribute__((ext_vector_type(8))) unsigned short;
using short8   = __attribute__((ext_vector_type(8))) short;
using f32x4    = __attribute__((ext_vector_type(4))) float;
using float4v  = __attribute__((ext_vector_type(4))) float;

#define TPB 256

static inline int cdiv_l(long a, int b){ return (int)((a + b - 1) / b); }

__device__ __forceinline__ float b2f(unsigned short u){
  union { unsigned int i; float f; } v; v.i = ((unsigned int)u) << 16; return v.f;
}
__device__ __forceinline__ unsigned short f2b(float f){
  union { bf16 h; unsigned short u; } v; v.h = __float2bfloat16(f); return v.u;
}
__device__ __forceinline__ ushort8 bnApply8(ushort8 v, const float* sc, const float* sh, int c){
  float4v s0 = *(const float4v*)(sc + c), s1v = *(const float4v*)(sc + c + 4);
  float4v h0 = *(const float4v*)(sh + c), h1v = *(const float4v*)(sh + c + 4);
  ushort8 r;
#pragma unroll
  for (int j = 0; j < 4; ++j){ float y = b2f(v[j]) * s0[j] + h0[j]; r[j] = f2b(y > 0.f ? y : 0.f); }
#pragma unroll
  for (int j = 0; j < 4; ++j){ float y = b2f(v[j+4]) * s1v[j] + h1v[j]; r[j+4] = f2b(y > 0.f ? y : 0.f); }
  return r;
}

// ---------------- merged weight repack ----------------
__global__ void rp_all(const float* __restrict__ w0, const float* __restrict__ w1,
                       const float* __restrict__ w2, const float* __restrict__ wt2r,
                       const float* __restrict__ wt2c, const float* __restrict__ wt1r,
                       const float* __restrict__ wt1c, const float* __restrict__ wt0r,
                       const float* __restrict__ wt0c,
                       unsigned short* __restrict__ wb0p, unsigned short* __restrict__ wb1,
                       unsigned short* __restrict__ wb2, unsigned short* __restrict__ wb2r,
                       unsigned short* __restrict__ wb2c, unsigned short* __restrict__ wb1r,
                       unsigned short* __restrict__ wb1c, unsigned short* __restrict__ wbrec,
                       unsigned short* __restrict__ wbcl){
  int idx = blockIdx.x * TPB + threadIdx.x;
  auto enc = [](const float* w, unsigned short* d, int i, int Cin, int Cout){
    int ci = i % Cin; int t = i / Cin; int co = t % Cout; int tap = t / Cout;
    d[i] = f2b(w[((long)co * Cin + ci) * 27 + tap]);
  };
  auto dec = [](const float* w, unsigned short* d, int i, int Cin, int Cout, int CIP, int COP){
    int ci = i % CIP; int t = i / CIP; int co = t % COP; int tap = t / COP;
    float v = (ci < Cin && co < Cout) ? w[((long)tap * Cin + ci) * Cout + co] : 0.f;
    d[i] = f2b(v);
  };
  if (idx < 14336) {
    int i = idx;
    int k = i & 31; int t = i >> 5; int co = t & 31; int pp = t >> 5;
    int tap = pp * 2 + (k >> 4); int ci = k & 15;
    float v = (tap < 27) ? w0[((long)co * 16 + ci) * 27 + tap] : 0.f;
    wb0p[i] = f2b(v);
  }
  else if (idx <   69632) enc(w1,  wb1,  idx - 14336,  32, 64);
  else if (idx <  290816) enc(w2,  wb2,  idx - 69632,  64, 128);
  else if (idx <  512000) dec(wt2r, wb2r, idx - 290816, 128, 64, 128, 64);
  else if (idx <  733184) dec(wt2c, wb2c, idx - 512000, 128, 64, 128, 64);
  else if (idx <  788480) dec(wt1r, wb1r, idx - 733184,  64, 32,  64, 32);
  else if (idx < 1009664) dec(wt1c, wb1c, idx - 788480, 128, 64, 128, 64);
  else if (idx < 1023488) dec(wt0r, wbrec, idx - 1009664, 32, 16,  32, 16);
  else if (idx < 1064960) dec(wt0c, wbcl, idx - 1023488, 96,  2,  96, 16);
}

// ---------------- x transpose: NCDHW fp32 -> NDHWC bf16 (C=16) ----------------
__global__ void xpose_k(const float* __restrict__ x, unsigned short* __restrict__ xt){
  __shared__ float l[16][257];
  int t = threadIdx.x;
  long p0 = (long)blockIdx.x * 256;
  int n = (int)(p0 >> 18);
  long off = p0 & 262143;
  const float* xb = x + ((long)n * 16) * 262144 + off;
#pragma unroll
  for (int c = 0; c < 16; ++c) l[c][t] = xb[(long)c * 262144 + t];
  __syncthreads();
  ushort8 u0, u1;
#pragma unroll
  for (int k = 0; k < 8; ++k){ u0[k] = f2b(l[k][t]); u1[k] = f2b(l[k + 8][t]); }
  unsigned short* o = xt + (p0 + t) * 16;
  *(ushort8*)o = u0; *(ushort8*)(o + 8) = u1;
}

// ---------------- quadrant stride-2 tconv, dbuf LDS, optional fused stats ----
template <int CO_TILES, bool STATS>
__global__ __launch_bounds__(TPB, 2) void tconv_quad(
    const unsigned short* __restrict__ inA, int CA,
    const unsigned short* __restrict__ inB, int CB,
    const float* __restrict__ scA, const float* __restrict__ shA,
    const unsigned short* __restrict__ wb,
    unsigned short* __restrict__ out,
    float* __restrict__ part2, int NB,
    int N, int Cout, int COP, int CIP, int G) {
  __shared__ unsigned short xs[2][4 * 432 * 8];
  const int tid = threadIdx.x, wv = tid >> 6, l = tid & 63, l15 = l & 15, lg = l >> 4;
  int ntW = G >> 4, ntH = G >> 2, ntD = G >> 2;
  int bx = blockIdx.x;
  const int blkLin = blockIdx.x * 4 + blockIdx.z;
  int w0 = (bx % ntW) << 4; bx /= ntW;
  int h0 = (bx % ntH) << 2; bx /= ntH;
  int d0 = (bx % ntD) << 2; int n = bx / ntD;
  const int co0 = blockIdx.y * (16 * CO_TILES);
  const int quad = blockIdx.z;
  const int pd = (quad >> 1) & 1, ph = quad & 1;
  const long spin = (long)G * G * G;

  int nkd, kd_[2], dd_[2], nkh, kh_[2], dh_[2];
  if (pd){ nkd=1; kd_[0]=1; dd_[0]=0; } else { nkd=2; kd_[0]=0; dd_[0]=-1; kd_[1]=2; dd_[1]=0; }
  if (ph){ nkh=1; kh_[0]=1; dh_[0]=0; } else { nkh=2; kh_[0]=0; dh_[0]=-1; kh_[1]=2; dh_[1]=0; }

  f32x4 acc[CO_TILES][4][2];
#pragma unroll
  for (int ct = 0; ct < CO_TILES; ++ct)
#pragma unroll
    for (int j = 0; j < 4; ++j)
#pragma unroll
      for (int p = 0; p < 2; ++p) acc[ct][j][p] = (f32x4){0.f, 0.f, 0.f, 0.f};

  auto stage = [&](int ch, int buf) {
    int c0 = ch << 5;
    const unsigned short* src; int Cs, cl_; bool useBN;
    if (c0 < CA){ src = inA; Cs = CA; cl_ = c0; useBN = (scA != nullptr); }
    else        { src = inB; Cs = CB; cl_ = c0 - CA; useBN = false; }
    const unsigned short* sb = src + (long)n * Cs * spin;
    unsigned short* xb = &xs[buf][0];
    for (int idx = tid; idx < 4 * 425; idx += TPB) {
      int q = idx / 425, pt = idx - q * 425;
      int zw = pt % 17; int zt = pt / 17; int zh = zt % 5; int zd = zt / 5;
      int gd = d0 + zd - 1, gh = h0 + zh - 1, gw = w0 + zw - 1;
      ushort8 v = (ushort8){0,0,0,0,0,0,0,0};
      if ((unsigned)gd < (unsigned)G && (unsigned)gh < (unsigned)G && (unsigned)gw < (unsigned)G) {
        v = *(const ushort8*)(sb + (((long)gd * G + gh) * G + gw) * Cs + cl_ + q * 8);
        if (useBN) v = bnApply8(v, scA, shA, cl_ + q * 8);
      }
      *(ushort8*)(xb + (q * 432 + pt) * 8) = v;
    }
  };

  const int nch = CIP >> 5;
  stage(0, 0);
  __syncthreads();
#pragma unroll 1
  for (int ch = 0; ch < nch; ++ch) {
    int cur = ch & 1;
    int c0 = ch << 5;
    if (ch + 1 < nch) stage(ch + 1, cur ^ 1);
    const unsigned short* xr = &xs[cur][0];
#pragma unroll 1
    for (int a = 0; a < nkd; ++a) {
      int zd = wv + 1 + dd_[a];
#pragma unroll 1
      for (int b = 0; b < nkh; ++b) {
        int tapb = (kd_[a] * 3 + kh_[b]) * 3;
        const unsigned short* ap = wb + ((long)tapb * COP + co0 + l15) * CIP + c0 + lg * 8;
        long tstride = (long)COP * CIP;
        short8 Ak0[CO_TILES], Ak1[CO_TILES], Ak2[CO_TILES];
#pragma unroll
        for (int ct = 0; ct < CO_TILES; ++ct) {
          Ak0[ct] = *(const short8*)(ap + ct * 16 * CIP);
          Ak1[ct] = *(const short8*)(ap + tstride + ct * 16 * CIP);
          Ak2[ct] = *(const short8*)(ap + 2 * tstride + ct * 16 * CIP);
        }
        int zh0 = 1 + dh_[b];
#pragma unroll
        for (int j = 0; j < 4; ++j) {
          int basept = (zd * 5 + (j + zh0)) * 17 + l15;
          short8 Bm = *(const short8*)(xr + (lg * 432 + basept) * 8);
          short8 B0 = *(const short8*)(xr + (lg * 432 + basept + 1) * 8);
#pragma unroll
          for (int ct = 0; ct < CO_TILES; ++ct) {
            acc[ct][j][0] = __builtin_amdgcn_mfma_f32_16x16x32_bf16(Ak0[ct], Bm, acc[ct][j][0], 0, 0, 0);
            acc[ct][j][0] = __builtin_amdgcn_mfma_f32_16x16x32_bf16(Ak2[ct], B0, acc[ct][j][0], 0, 0, 0);
            acc[ct][j][1] = __builtin_amdgcn_mfma_f32_16x16x32_bf16(Ak1[ct], B0, acc[ct][j][1], 0, 0, 0);
          }
        }
      }
    }
    __syncthreads();
  }

  // ---- dense store ----
  int Gout = 2 * G; long spo = (long)Gout * Gout * Gout;
  int od = 2 * (d0 + wv) + pd;
#pragma unroll
  for (int j = 0; j < 4; ++j) {
    int oh = 2 * (h0 + j) + ph;
#pragma unroll
    for (int p = 0; p < 2; ++p) {
      int ow = 2 * (w0 + l15) + p;
      long pt = ((long)od * Gout + oh) * Gout + ow;
#pragma unroll
      for (int ct = 0; ct < CO_TILES; ++ct) {
        ushort4v pk;
#pragma unroll
        for (int r = 0; r < 4; ++r) pk[r] = f2b(acc[ct][j][p][r]);
        *(ushort4v*)(out + ((long)n * spo + pt) * Cout + co0 + ct * 16 + lg * 4) = pk;
      }
    }
  }

  if constexpr (STATS) {
    __shared__ float redS[4][CO_TILES][4][4];
    __shared__ float redQ[4][CO_TILES][4][4];
#pragma unroll
    for (int ct = 0; ct < CO_TILES; ++ct)
#pragma unroll
      for (int r = 0; r < 4; ++r) {
        float s = 0.f, q = 0.f;
#pragma unroll
        for (int j = 0; j < 4; ++j)
#pragma unroll
          for (int p = 0; p < 2; ++p) { float a = acc[ct][j][p][r]; s += a; q += a * a; }
#pragma unroll
        for (int m = 1; m < 16; m <<= 1) { s += __shfl_xor(s, m); q += __shfl_xor(q, m); }
        if (l15 == 0) { redS[wv][ct][lg][r] = s; redQ[wv][ct][lg][r] = q; }
      }
    __syncthreads();
    if (tid < CO_TILES * 16) {
      int ct = tid >> 4, lg2 = (tid >> 2) & 3, r = tid & 3;
      float s = 0.f, q = 0.f;
#pragma unroll
      for (int w2 = 0; w2 < 4; ++w2) { s += redS[w2][ct][lg2][r]; q += redQ[w2][ct][lg2][r]; }
      int c = co0 + ct * 16 + lg2 * 4 + r;
      long slot = (long)c * NB + blkLin;
      part2[slot * 2] = s; part2[slot * 2 + 1] = q;
    }
  }
}

// ---------------- dual-head quadrant tconv2 (shared s4 staging) ------------
// heads: A -> outA (wbA), B -> outB (wbB). Single-buffer LDS; always stats.
__global__ __launch_bounds__(TPB) void tconv_dual(
    const unsigned short* __restrict__ in, int CI,
    const float* __restrict__ scA, const float* __restrict__ shA,
    const unsigned short* __restrict__ wbA, const unsigned short* __restrict__ wbB,
    unsigned short* __restrict__ outA, unsigned short* __restrict__ outB,
    float* __restrict__ p2A, float* __restrict__ p2B, int NB,
    int N, int Cout, int COP, int CIP, int G) {
  const int CT = 2;
  __shared__ unsigned short xs[4 * 432 * 8];
  const int tid = threadIdx.x, wv = tid >> 6, l = tid & 63, l15 = l & 15, lg = l >> 4;
  int ntW = G >> 4, ntH = G >> 2, ntD = G >> 2;
  int bx = blockIdx.x;
  const int blkLin = blockIdx.x * 4 + blockIdx.z;
  int w0 = (bx % ntW) << 4; bx /= ntW;
  int h0 = (bx % ntH) << 2; bx /= ntH;
  int d0 = (bx % ntD) << 2; int n = bx / ntD;
  const int co0 = blockIdx.y * (16 * CT);
  const int quad = blockIdx.z;
  const int pd = (quad >> 1) & 1, ph = quad & 1;
  const long spin = (long)G * G * G;

  int nkd, kd_[2], dd_[2], nkh, kh_[2], dh_[2];
  if (pd){ nkd=1; kd_[0]=1; dd_[0]=0; } else { nkd=2; kd_[0]=0; dd_[0]=-1; kd_[1]=2; dd_[1]=0; }
  if (ph){ nkh=1; kh_[0]=1; dh_[0]=0; } else { nkh=2; kh_[0]=0; dh_[0]=-1; kh_[1]=2; dh_[1]=0; }

  f32x4 acc[2][CT][4][2];
#pragma unroll
  for (int h = 0; h < 2; ++h)
#pragma unroll
    for (int ct = 0; ct < CT; ++ct)
#pragma unroll
      for (int j = 0; j < 4; ++j)
#pragma unroll
        for (int p = 0; p < 2; ++p) acc[h][ct][j][p] = (f32x4){0.f, 0.f, 0.f, 0.f};

  const int nch = CIP >> 5;
#pragma unroll 1
  for (int ch = 0; ch < nch; ++ch) {
    int c0 = ch << 5;
    const unsigned short* sb = in + (long)n * CI * spin;
    __syncthreads();
    for (int idx = tid; idx < 4 * 425; idx += TPB) {
      int q = idx / 425, pt = idx - q * 425;
      int zw = pt % 17; int zt = pt / 17; int zh = zt % 5; int zd = zt / 5;
      int gd = d0 + zd - 1, gh = h0 + zh - 1, gw = w0 + zw - 1;
      ushort8 v = (ushort8){0,0,0,0,0,0,0,0};
      if ((unsigned)gd < (unsigned)G && (unsigned)gh < (unsigned)G && (unsigned)gw < (unsigned)G) {
        v = *(const ushort8*)(sb + (((long)gd * G + gh) * G + gw) * CI + c0 + q * 8);
        v = bnApply8(v, scA, shA, c0 + q * 8);
      }
      *(ushort8*)(xs + (q * 432 + pt) * 8) = v;
    }
    __syncthreads();
#pragma unroll 1
    for (int a = 0; a < nkd; ++a) {
      int zd = wv + 1 + dd_[a];
#pragma unroll 1
      for (int b = 0; b < nkh; ++b) {
        int tapb = (kd_[a] * 3 + kh_[b]) * 3;
        long tstride = (long)COP * CIP;
        long abase = ((long)tapb * COP + co0 + l15) * CIP + c0 + lg * 8;
        int zh0 = 1 + dh_[b];
#pragma unroll
        for (int h = 0; h < 2; ++h) {
          const unsigned short* ap = (h == 0 ? wbA : wbB) + abase;
          short8 Ak0[CT], Ak1[CT], Ak2[CT];
#pragma unroll
          for (int ct = 0; ct < CT; ++ct) {
            Ak0[ct] = *(const short8*)(ap + ct * 16 * CIP);
            Ak1[ct] = *(const short8*)(ap + tstride + ct * 16 * CIP);
            Ak2[ct] = *(const short8*)(ap + 2 * tstride + ct * 16 * CIP);
          }
#pragma unroll
          for (int j = 0; j < 4; ++j) {
            int basept = (zd * 5 + (j + zh0)) * 17 + l15;
            short8 Bm = *(const short8*)(xs + (lg * 432 + basept) * 8);
            short8 B0 = *(const short8*)(xs + (lg * 432 + basept + 1) * 8);
#pragma unroll
            for (int ct = 0; ct < CT; ++ct) {
              acc[h][ct][j][0] = __builtin_amdgcn_mfma_f32_16x16x32_bf16(Ak0[ct], Bm, acc[h][ct][j][0], 0, 0, 0);
              acc[h][ct][j][0] = __builtin_amdgcn_mfma_f32_16x16x32_bf16(Ak2[ct], B0, acc[h][ct][j][0], 0, 0, 0);
              acc[h][ct][j][1] = __builtin_amdgcn_mfma_f32_16x16x32_bf16(Ak1[ct], B0, acc[h][ct][j][1], 0, 0, 0);
            }
          }
        }
      }
    }
  }

  // ---- dense store (both heads) ----
  int Gout = 2 * G; long spo = (long)Gout * Gout * Gout;
  int od = 2 * (d0 + wv) + pd;
#pragma unroll
  for (int j = 0; j < 4; ++j) {
    int oh = 2 * (h0 + j) + ph;
#pragma unroll
    for (int p = 0; p < 2; ++p) {
      int ow = 2 * (w0 + l15) + p;
      long pt = ((long)od * Gout + oh) * Gout + ow;
#pragma unroll
      for (int h = 0; h < 2; ++h) {
        unsigned short* o = h == 0 ? outA : outB;
#pragma unroll
        for (int ct = 0; ct < CT; ++ct) {
          ushort4v pk;
#pragma unroll
          for (int r = 0; r < 4; ++r) pk[r] = f2b(acc[h][ct][j][p][r]);
          *(ushort4v*)(o + ((long)n * spo + pt) * Cout + co0 + ct * 16 + lg * 4) = pk;
        }
      }
    }
  }

  // ---- stats, two rounds ----
  __shared__ float redS[4][CT][4][4];
  __shared__ float redQ[4][CT][4][4];
#pragma unroll 1
  for (int h = 0; h < 2; ++h) {
    __syncthreads();
#pragma unroll
    for (int ct = 0; ct < CT; ++ct)
#pragma unroll
      for (int r = 0; r < 4; ++r) {
        float s = 0.f, q = 0.f;
#pragma unroll
        for (int j = 0; j < 4; ++j)
#pragma unroll
          for (int p = 0; p < 2; ++p) { float a = acc[h][ct][j][p][r]; s += a; q += a * a; }
#pragma unroll
        for (int m = 1; m < 16; m <<= 1) { s += __shfl_xor(s, m); q += __shfl_xor(q, m); }
        if (l15 == 0) { redS[wv][ct][lg][r] = s; redQ[wv][ct][lg][r] = q; }
      }
    __syncthreads();
    if (tid < CT * 16) {
      int ct = tid >> 4, lg2 = (tid >> 2) & 3, r = tid & 3;
      float s = 0.f, q = 0.f;
#pragma unroll
      for (int w2 = 0; w2 < 4; ++w2) { s += redS[w2][ct][lg2][r]; q += redQ[w2][ct][lg2][r]; }
      int c = co0 + ct * 16 + lg2 * 4 + r;
      long slot = (long)c * NB + blkLin;
      float* p2 = h == 0 ? p2A : p2B;
      p2[slot * 2] = s; p2[slot * 2 + 1] = q;
    }
  }
}

// ---------------- unified NDHWC MFMA conv ----------------
// VARIANT 0 / PAIRED: stride-1 conv, LDS-staged, tile 2d x 8h x 16w.
// VARIANT 2: stride-2 conv, direct-global B, tile 4d x 4h x 16w.
template <int VARIANT, int CO_TILES, bool PAIRED, bool FOUT, bool STATS>
__global__ __launch_bounds__(TPB) void mconv(
    const unsigned short* __restrict__ inA, int CA,
    const unsigned short* __restrict__ inB, int CB,
    const float* __restrict__ scA, const float* __restrict__ shA,
    const unsigned short* __restrict__ wb,
    void* __restrict__ outv,
    float* __restrict__ part2, int NB,
    int N, int Cout, int COP, int CIP, int G) {
  const int tid = threadIdx.x, wv = tid >> 6, l = tid & 63, l15 = l & 15, lg = l >> 4;
  int bx = blockIdx.x;
  const int blkLin = blockIdx.x;
  int w0, h0, d0, n;
  int wvd = wv & 1, jh = wv >> 1, jbase = jh * 4;
  if constexpr (VARIANT == 0) {
    int ntW = G >> 4, ntH = G >> 3, ntD = G >> 1;
    w0 = (bx % ntW) << 4; bx /= ntW;
    h0 = (bx % ntH) << 3; bx /= ntH;
    d0 = (bx % ntD) << 1; n = bx / ntD;
  } else {
    int ntW = G >> 4, ntH = G >> 2, ntD = G >> 2;
    w0 = (bx % ntW) << 4; bx /= ntW;
    h0 = (bx % ntH) << 2; bx /= ntH;
    d0 = (bx % ntD) << 2; n = bx / ntD;
  }
  const int co0 = blockIdx.y * (16 * CO_TILES);
  const int Gin = (VARIANT == 2) ? 2 * G : G;
  const long spin = (long)Gin * Gin * Gin;

  f32x4 acc[CO_TILES][4];
#pragma unroll
  for (int ct = 0; ct < CO_TILES; ++ct)
#pragma unroll
    for (int j = 0; j < 4; ++j) acc[ct][j] = (f32x4){0.f, 0.f, 0.f, 0.f};

  if constexpr (PAIRED) {
    __shared__ unsigned short xs[2 * 728 * 8];
    const unsigned short* src = inA + (long)n * 16 * spin;
    for (int idx = tid; idx < 2 * 720; idx += TPB) {
      int q = idx / 720, pt = idx - q * 720;
      int zw = pt % 18; int zt = pt / 18; int zh = zt % 10; int zd = zt / 10;
      int gd = d0 + zd - 1, gh = h0 + zh - 1, gw = w0 + zw - 1;
      ushort8 v = (ushort8){0,0,0,0,0,0,0,0};
      if ((unsigned)gd < (unsigned)G && (unsigned)gh < (unsigned)G && (unsigned)gw < (unsigned)G)
        v = *(const ushort8*)(src + (((long)gd * G + gh) * G + gw) * 16 + q * 8);
      *(ushort8*)(xs + (q * 728 + pt) * 8) = v;
    }
    __syncthreads();
#pragma unroll 1
    for (int pp = 0; pp < 14; ++pp) {
      short8 A0 = *(const short8*)(wb + ((pp * 32 + l15) * 32) + lg * 8);
      short8 A1 = *(const short8*)(wb + ((pp * 32 + 16 + l15) * 32) + lg * 8);
      int t0 = 2 * pp + (lg >> 1); if (t0 > 26) t0 = 26;
      int dd = t0 / 9 - 1, dh = (t0 / 3) % 3 - 1, dw = t0 % 3 - 1;
      int q = lg & 1;
      int zd = wvd + 1 + dd;
      int base = (q * 728 + (zd * 10 + (1 + dh + jbase)) * 18 + 1 + l15 + dw) * 8;
#pragma unroll
      for (int j = 0; j < 4; ++j) {
        short8 B = *(const short8*)(xs + base + j * (18 * 8));
        acc[0][j] = __builtin_amdgcn_mfma_f32_16x16x32_bf16(A0, B, acc[0][j], 0, 0, 0);
        if (CO_TILES == 2)
          acc[1][j] = __builtin_amdgcn_mfma_f32_16x16x32_bf16(A1, B, acc[1][j], 0, 0, 0);
      }
    }
  } else if constexpr (VARIANT == 0) {
    __shared__ unsigned short xs[4 * 728 * 8];
    const int nch = CIP >> 5;
#pragma unroll 1
    for (int ch = 0; ch < nch; ++ch) {
      int c0 = ch << 5;
      const unsigned short* src; int Cs, cl_; bool useBN;
      if (c0 < CA){ src = inA; Cs = CA; cl_ = c0; useBN = (scA != nullptr); }
      else        { src = inB; Cs = CB; cl_ = c0 - CA; useBN = false; }
      const unsigned short* sb = src + (long)n * Cs * spin;
      __syncthreads();
      for (int idx = tid; idx < 4 * 720; idx += TPB) {
        int q = idx / 720, pt = idx - q * 720;
        int zw = pt % 18; int zt = pt / 18; int zh = zt % 10; int zd = zt / 10;
        int gd = d0 + zd - 1, gh = h0 + zh - 1, gw = w0 + zw - 1;
        ushort8 v = (ushort8){0,0,0,0,0,0,0,0};
        if ((unsigned)gd < (unsigned)G && (unsigned)gh < (unsigned)G && (unsigned)gw < (unsigned)G) {
          v = *(const ushort8*)(sb + (((long)gd * G + gh) * G + gw) * Cs + cl_ + q * 8);
          if (useBN) v = bnApply8(v, scA, shA, cl_ + q * 8);
        }
        *(ushort8*)(xs + (q * 728 + pt) * 8) = v;
      }
      __syncthreads();
#pragma unroll 1
      for (int a = 0; a < 3; ++a) {
        int zd = wvd + a;
        short8 A0[3][3], A1[3][3];
#pragma unroll
        for (int b = 0; b < 3; ++b)
#pragma unroll
          for (int c = 0; c < 3; ++c) {
            int tap = (a * 3 + b) * 3 + c;
            const unsigned short* ap = wb + ((long)tap * COP + co0 + l15) * CIP + c0 + lg * 8;
            A0[b][c] = *(const short8*)ap;
            if (CO_TILES == 2) A1[b][c] = *(const short8*)(ap + 16 * CIP);
          }
#pragma unroll
        for (int sl = 0; sl < 6; ++sl) {
          int sg = jbase + sl;
          int rb = (lg * 728 + (zd * 10 + sg) * 18 + l15) * 8;
          short8 B0 = *(const short8*)(xs + rb);
          short8 B1 = *(const short8*)(xs + rb + 8);
          short8 B2 = *(const short8*)(xs + rb + 16);
#pragma unroll
          for (int b = 0; b < 3; ++b) {
            int j = sl - b;
            if (j >= 0 && j < 4) {
              acc[0][j] = __builtin_amdgcn_mfma_f32_16x16x32_bf16(A0[b][0], B0, acc[0][j], 0, 0, 0);
              acc[0][j] = __builtin_amdgcn_mfma_f32_16x16x32_bf16(A0[b][1], B1, acc[0][j], 0, 0, 0);
              acc[0][j] = __builtin_amdgcn_mfma_f32_16x16x32_bf16(A0[b][2], B2, acc[0][j], 0, 0, 0);
              if (CO_TILES == 2) {
                acc[1][j] = __builtin_amdgcn_mfma_f32_16x16x32_bf16(A1[b][0], B0, acc[1][j], 0, 0, 0);
                acc[1][j] = __builtin_amdgcn_mfma_f32_16x16x32_bf16(A1[b][1], B1, acc[1][j], 0, 0, 0);
                acc[1][j] = __builtin_amdgcn_mfma_f32_16x16x32_bf16(A1[b][2], B2, acc[1][j], 0, 0, 0);
              }
            }
          }
        }
      }
    }
  } else {
    const int nch = CIP >> 5;
#pragma unroll 1
    for (int ch = 0; ch < nch; ++ch) {
      int c0 = ch << 5;
      const unsigned short* src; int Cs, cl_;
      if (c0 < CA){ src = inA; Cs = CA; cl_ = c0; } else { src = inB; Cs = CB; cl_ = c0 - CA; }
      const unsigned short* sb = src + (long)n * Cs * spin;
#pragma unroll 1
      for (int a = 0; a < 3; ++a) {
        int gd = 2 * (d0 + wv) + a - 1;
        bool vd = (unsigned)gd < (unsigned)Gin;
#pragma unroll 1
        for (int b = 0; b < 3; ++b) {
#pragma unroll
          for (int c = 0; c < 3; ++c) {
            int tap = (a * 3 + b) * 3 + c;
            const unsigned short* ap = wb + ((long)tap * COP + co0 + l15) * CIP + c0 + lg * 8;
            short8 A0 = *(const short8*)ap;
            short8 A1;
            if (CO_TILES == 2) A1 = *(const short8*)(ap + 16 * CIP);
            int gw = 2 * (w0 + l15) + c - 1;
            bool vdw = vd && ((unsigned)gw < (unsigned)Gin);
#pragma unroll
            for (int j = 0; j < 4; ++j) {
              int gh = 2 * (h0 + j) + b - 1;
              short8 B = (short8){0,0,0,0,0,0,0,0};
              if (vdw && (unsigned)gh < (unsigned)Gin)
                B = *(const short8*)(sb + (((long)gd * Gin + gh) * Gin + gw) * Cs + cl_ + lg * 8);
              acc[0][j] = __builtin_amdgcn_mfma_f32_16x16x32_bf16(A0, B, acc[0][j], 0, 0, 0);
              if (CO_TILES == 2)
                acc[1][j] = __builtin_amdgcn_mfma_f32_16x16x32_bf16(A1, B, acc[1][j], 0, 0, 0);
            }
          }
        }
      }
    }
  }

  // ---- store ----
  const long spo = (long)G * G * G;
#pragma unroll
  for (int j = 0; j < 4; ++j) {
    long pt;
    if constexpr (VARIANT == 0)
      pt = ((long)(d0 + wvd) * G + (h0 + jbase + j)) * G + (w0 + l15);
    else
      pt = ((long)(d0 + wv) * G + (h0 + j)) * G + (w0 + l15);
    if constexpr (!FOUT) {
      unsigned short* outp = (unsigned short*)outv;
#pragma unroll
      for (int ct = 0; ct < CO_TILES; ++ct) {
        ushort4v pk;
#pragma unroll
        for (int r = 0; r < 4; ++r) pk[r] = f2b(acc[ct][j][r]);
        *(ushort4v*)(outp + ((long)n * spo + pt) * Cout + co0 + ct * 16 + lg * 4) = pk;
      }
    } else {
      float* outp = (float*)outv;
#pragma unroll
      for (int ct = 0; ct < CO_TILES; ++ct)
#pragma unroll
        for (int r = 0; r < 4; ++r) {
          int co = co0 + ct * 16 + lg * 4 + r;
          if (co < Cout) outp[((long)(n * Cout + co)) * spo + pt] = acc[ct][j][r];
        }
    }
  }

  if constexpr (STATS) {
    __shared__ float redS[4][CO_TILES][4][4];
    __shared__ float redQ[4][CO_TILES][4][4];
#pragma unroll
    for (int ct = 0; ct < CO_TILES; ++ct)
#pragma unroll
      for (int r = 0; r < 4; ++r) {
        float s = 0.f, q = 0.f;
#pragma unroll
        for (int j = 0; j < 4; ++j) { float a = acc[ct][j][r]; s += a; q += a * a; }
#pragma unroll
        for (int m = 1; m < 16; m <<= 1) { s += __shfl_xor(s, m); q += __shfl_xor(q, m); }
        if (l15 == 0) { redS[wv][ct][lg][r] = s; redQ[wv][ct][lg][r] = q; }
      }
    __syncthreads();
    if (tid < CO_TILES * 16) {
      int ct = tid >> 4, lg2 = (tid >> 2) & 3, r = tid & 3;
      float s = 0.f, q = 0.f;
#pragma unroll
      for (int w2 = 0; w2 < 4; ++w2) { s += redS[w2][ct][lg2][r]; q += redQ[w2][ct][lg2][r]; }
      int c = co0 + ct * 16 + lg2 * 4 + r;
      long slot = (long)c * NB + blkLin;
      part2[slot * 2] = s; part2[slot * 2 + 1] = q;
    }
  }
}

// ---------------- stats reduce: part2 -> scale/shift ----------------
__global__ void bn_stats2b(const float* __restrict__ part2, const float* __restrict__ g,
                           const float* __restrict__ b, float* __restrict__ sc,
                           float* __restrict__ sh, int NB, float inv_cnt){
  int c = blockIdx.x, tid = threadIdx.x;
  float s = 0.f, q = 0.f;
  for (int i = tid; i < NB; i += TPB) {
    s += part2[((long)c * NB + i) * 2];
    q += part2[((long)c * NB + i) * 2 + 1];
  }
  __shared__ float ss[TPB], qq[TPB];
  ss[tid] = s; qq[tid] = q;
  __syncthreads();
  for (int off = TPB / 2; off > 0; off >>= 1) {
    if (tid < off) { ss[tid] += ss[tid + off]; qq[tid] += qq[tid + off]; }
    __syncthreads();
  }
  if (tid == 0) {
    float m = ss[0] * inv_cnt, v = qq[0] * inv_cnt - m * m;
    float rs = rsqrtf(v + 1e-5f) * g[c];
    sc[c] = rs;
    sh[c] = b[c] - m * rs;
  }
}

// ---------------- BN apply + ReLU pass (for s1, s2 only) ----------------
__global__ void bn_relu_cl(unsigned short* __restrict__ x, const float* __restrict__ sc,
                           const float* __restrict__ sh, int C, long tot8){
  long i8 = (long)blockIdx.x * TPB + threadIdx.x;
  if (i8 >= tot8) return;
  long e = i8 * 8;
  int c0 = (int)(e & (C - 1));
  ushort8 v = *(ushort8*)(x + e);
  *(ushort8*)(x + e) = bnApply8(v, sc, sh, c0);
}

extern "C" void kernel_launch(void* const* d_in, const int* in_sizes, int n_in,
                              void* d_out, int out_size, void* d_ws, size_t ws_size,
                              hipStream_t stream) {
  const float* x    = (const float*)d_in[0];
  const float* w0   = (const float*)d_in[1];
  const float* g0   = (const float*)d_in[2];
  const float* b0   = (const float*)d_in[3];
  const float* w1   = (const float*)d_in[4];
  const float* g1   = (const float*)d_in[5];
  const float* b1   = (const float*)d_in[6];
  const float* w2   = (const float*)d_in[7];
  const float* g2   = (const float*)d_in[8];
  const float* b2   = (const float*)d_in[9];
  const float* wt2r = (const float*)d_in[10];
  const float* g2r  = (const float*)d_in[11];
  const float* b2r  = (const float*)d_in[12];
  const float* wt1r = (const float*)d_in[13];
  const float* g1r  = (const float*)d_in[14];
  const float* b1r  = (const float*)d_in[15];
  const float* wt0r = (const float*)d_in[16];
  const float* wt2c = (const float*)d_in[17];
  const float* g2c  = (const float*)d_in[18];
  const float* b2c  = (const float*)d_in[19];
  const float* wt1c = (const float*)d_in[20];
  const float* g1c  = (const float*)d_in[21];
  const float* b1c  = (const float*)d_in[22];
  const float* wt0c = (const float*)d_in[23];

  const int N = 2;
  const long sp64 = 262144, sp32 = 32768, sp16 = 4096;

  // ---- workspace (ushort units), all activations NDHWC bf16 ----
  unsigned short* W = (unsigned short*)d_ws;
  unsigned short* s1   = W;                       // [2*sp64][32]
  unsigned short* s2   = s1  + 16777216;          // [2*sp32][64]
  unsigned short* s4   = s2  + 4194304;           // [2*sp16][128]
  unsigned short* r32  = s4  + 1048576;           // [2*sp32][64]
  unsigned short* c32  = r32 + 4194304;           // [2*sp32][64]
  unsigned short* r64  = c32 + 4194304;           // [2*sp64][32]
  unsigned short* xt   = r64;                     // alias (dead after conv0)
  unsigned short* c64  = r64 + 16777216;          // [2*sp64][64]
  unsigned short* wb0p = c64 + 33554432;          // 14*32*32
  unsigned short* wb1  = wb0p + 14336;            // 27*64*32
  unsigned short* wb2  = wb1  + 55296;            // 27*128*64
  unsigned short* wb2r = wb2  + 221184;           // 27*64*128
  unsigned short* wb2c = wb2r + 221184;
  unsigned short* wb1r = wb2c + 221184;           // 27*32*64
  unsigned short* wb1c = wb1r + 55296;            // 27*64*128
  unsigned short* wbrec= wb1c + 221184;           // 27*16*32
  unsigned short* wbcl = wbrec+ 13824;            // 27*16*96
  float* part2  = (float*)(wbcl + 41472);         // 131072 f32 (512KB)
  float* part2b = part2 + 131072;                 // 16384 f32 (64KB)
  float* bsc  = part2b + 16384;                   // shared (s1, s2)
  float* bsh  = bsc + 128;
  float* sc_s4  = bsh  + 128; float* sh_s4  = sc_s4  + 128;
  float* sc_r32 = sh_s4 + 128; float* sh_r32 = sc_r32 + 128;
  float* sc_c32 = sh_r32+ 128; float* sh_c32 = sc_c32 + 128;
  float* sc_r64 = sh_c32+ 128; float* sh_r64 = sc_r64 + 128;
  float* sc_c64 = sh_r64+ 128; float* sh_c64 = sc_c64 + 128;

  float* out_cl  = (float*)d_out;                 // [2][2][64^3] NCDHW
  float* out_rec = (float*)d_out + 2L * 2 * sp64; // [2][16][64^3]

  // ---- merged weight repack + x transpose ----
  rp_all<<<cdiv_l(1064960, TPB), TPB, 0, stream>>>(
      w0, w1, w2, wt2r, wt2c, wt1r, wt1c, wt0r, wt0c,
      wb0p, wb1, wb2, wb2r, wb2c, wb1r, wb1c, wbrec, wbcl);
  xpose_k<<<2048, TPB, 0, stream>>>(x, xt);

  auto gx0 = [&](int G){ return (unsigned)(N * (G >> 1) * (G >> 3) * (G >> 4)); };
  auto gx  = [&](int G){ return (unsigned)(N * (G >> 2) * (G >> 2) * (G >> 4)); };

  // ---- encoder ----
  // conv0 -> s1 (+ fused stats, NB=2048)
  mconv<0, 2, true, false, true><<<dim3(gx0(64), 1), TPB, 0, stream>>>(
      xt, 16, nullptr, 0, nullptr, nullptr, wb0p, s1, part2, (int)gx0(64), N, 32, 32, 32, 64);
  bn_stats2b<<<32, TPB, 0, stream>>>(part2, g0, b0, bsc, bsh, (int)gx0(64), 1.f / (float)(2 * sp64));
  bn_relu_cl<<<cdiv_l(2 * sp64 * 32 / 8, TPB), TPB, 0, stream>>>(s1, bsc, bsh, 32, 2 * sp64 * 32 / 8);

  // conv1 -> s2 (+ stats, NB=gx(32))
  mconv<2, 2, false, false, true><<<dim3(gx(32), 2), TPB, 0, stream>>>(
      s1, 32, nullptr, 0, nullptr, nullptr, wb1, s2, part2, (int)gx(32), N, 64, 64, 32, 32);
  bn_stats2b<<<64, TPB, 0, stream>>>(part2, g1, b1, bsc, bsh, (int)gx(32), 1.f / (float)(2 * sp32));
  bn_relu_cl<<<cdiv_l(2 * sp32 * 64 / 8, TPB), TPB, 0, stream>>>(s2, bsc, bsh, 64, 2 * sp32 * 64 / 8);

  // conv2 -> s4 (+ stats, NB=gx(16))
  mconv<2, 1, false, false, true><<<dim3(gx(16), 8), TPB, 0, stream>>>(
      s2, 64, nullptr, 0, nullptr, nullptr, wb2, s4, part2, (int)gx(16), N, 128, 128, 64, 16);
  bn_stats2b<<<128, TPB, 0, stream>>>(part2, g2, b2, sc_s4, sh_s4, (int)gx(16), 1.f / (float)(2 * sp16));

  // ---- level-2 dual tconv (s4 staged once) -> r32, c32 (+ both stats) ----
  tconv_dual<<<dim3(gx(16), 2, 4), TPB, 0, stream>>>(
      s4, 128, sc_s4, sh_s4, wb2r, wb2c, r32, c32, part2, part2b, (int)gx(16) * 4,
      N, 64, 64, 128, 16);
  bn_stats2b<<<64, TPB, 0, stream>>>(part2, g2r, b2r, sc_r32, sh_r32, (int)gx(16) * 4, 1.f / (float)(2 * sp32));
  bn_stats2b<<<64, TPB, 0, stream>>>(part2b, g2c, b2c, sc_c32, sh_c32, (int)gx(16) * 4, 1.f / (float)(2 * sp32));

  // ---- level-1 tconvs (32 -> 64), quadrants (+ stats) ----
  tconv_quad<2, true><<<dim3(gx(32), 1, 4), TPB, 0, stream>>>(
      r32, 64, nullptr, 0, sc_r32, sh_r32, wb1r, r64, part2, (int)gx(32) * 4, N, 32, 32, 64, 32);
  bn_stats2b<<<32, TPB, 0, stream>>>(part2, g1r, b1r, sc_r64, sh_r64, (int)gx(32) * 4, 1.f / (float)(2 * sp64));
  tconv_quad<4, true><<<dim3(gx(32), 1, 4), TPB, 0, stream>>>(
      c32, 64, s2, 64, sc_c32, sh_c32, wb1c, c64, part2, (int)gx(32) * 4, N, 64, 64, 128, 32);
  bn_stats2b<<<64, TPB, 0, stream>>>(part2, g1c, b1c, sc_c64, sh_c64, (int)gx(32) * 4, 1.f / (float)(2 * sp64));

  // ---- level-0 stride-1 convs (no BN on output), fused BN on inputs ----
  mconv<0, 1, false, true, false><<<dim3(gx0(64), 1), TPB, 0, stream>>>(
      r64, 32, nullptr, 0, sc_r64, sh_r64, wbrec, out_rec, nullptr, 0, N, 16, 16, 32, 64);
  mconv<0, 1, false, true, false><<<dim3(gx0(64), 1), TPB, 0, stream>>>(
      c64, 64, s1, 32, sc_c64, sh_c64, wbcl, out_cl, nullptr, 0, N, 2, 16, 96, 64);
}